// Round 5
// baseline (838.382 us; speedup 1.0000x reference)
//
#include <hip/hip_runtime.h>
#include <math.h>

typedef unsigned short ushort_t;
using short8  = __attribute__((ext_vector_type(8))) short;
using floatx4 = __attribute__((ext_vector_type(4))) float;

__device__ __forceinline__ ushort_t f2bf(float f) {
  unsigned u = __builtin_bit_cast(unsigned, f);
  u = (u + 0x7fffu + ((u >> 16) & 1u)) >> 16;
  return (ushort_t)u;
}
__device__ __forceinline__ float bf2f(ushort_t u) {
  unsigned v = ((unsigned)u) << 16;
  return __builtin_bit_cast(float, v);
}

__device__ __forceinline__ void load_lds16(const ushort_t* g, ushort_t* l) {
  __builtin_amdgcn_global_load_lds(
      (const __attribute__((address_space(1))) unsigned int*)g,
      (__attribute__((address_space(3))) unsigned int*)l, 16, 0, 0);
}

// ---------------- segmented batched GEMM (bf16 in, bf16 out) ----------------
// C[M,512] = (sum_s A_s[M,Ks] @ W_s^T + bias) * scale ; W_s stored [512,Ks] bf16
// A: global->LDS (swizzled, conflict-free, validated r4). B: DIRECT global->reg
// with one-tile register double-buffer (B is small + L2-resident; removes half
// of all LDS reads and half of staged bytes -> LDS-BW bound drops ~2x).
struct Seg { const ushort_t* A; const ushort_t* W; int lda, ldw, K; };
struct GemmZ {
  ushort_t* Cb;        // row-major [row*512+col] bf16 (may be null)
  ushort_t* CbT;       // transposed [col*512+row] bf16 (may be null; folds only, M=512)
  const float* bias;
  float scale; int nseg; int mmax;   // blocks with blockIdx.x >= mmax exit
  Seg seg[6];
};
struct GemmArgs { GemmZ z[9]; };

// TAG only differentiates kernel symbols per launch site for profiling.
template <int BM, int TAG>
__global__ __launch_bounds__(256) void gemm_bt(GemmArgs ga) {
  const GemmZ& gz = ga.z[blockIdx.z];
  if ((int)blockIdx.x >= gz.mmax) return;
  __shared__ ushort_t As[BM * 32];
  const int tid = threadIdx.x;
  const int wid = tid >> 6, lane = tid & 63, quad = lane >> 4, l16 = lane & 15;
  const int bm = blockIdx.x * BM, bn = blockIdx.y * 128;
  constexpr int MI = BM / 32;
  const int wm = (wid & 1) * (BM / 2), wn = (wid >> 1) * 64;
  floatx4 acc[MI][4] = {};
  const int srow = tid >> 2;
  const int scol = (((tid & 3) ^ ((tid >> 3) & 3))) * 8;   // bank-swizzled source col (A)
  const int qx   = (quad ^ ((l16 >> 1) & 3)) * 8;          // read-side inverse (A)
  ushort_t* aL = As + tid * 8;

  for (int s = 0; s < gz.nseg; s++) {
    const Seg sg = gz.seg[s];
    const ushort_t* aG = sg.A + (size_t)(bm + srow) * sg.lda + scol;
    const size_t astep = (size_t)64 * sg.lda;
    // per-wave B base: row = bn + wn + 16*j + l16, col = k + quad*8 (64B/row, L2-friendly)
    const ushort_t* bB = sg.W + (size_t)(bn + wn + l16) * sg.ldw + quad * 8;
    const size_t jstep = (size_t)16 * sg.ldw;
    short8 bw[4], bpf[4];
#pragma unroll
    for (int j = 0; j < 4; j++) bw[j] = *(const short8*)(bB + (size_t)j * jstep);
    for (int k0 = 0; k0 < sg.K; k0 += 32) {
      __syncthreads();
      load_lds16(aG + k0, aL);
      if constexpr (BM == 128) load_lds16(aG + k0 + astep, aL + 2048);
      __syncthreads();
      // prefetch next tile's B into registers; flight covered by MFMA + next stage
      const int kn = (k0 + 32 < sg.K) ? k0 + 32 : k0;
#pragma unroll
      for (int j = 0; j < 4; j++) bpf[j] = *(const short8*)(bB + (size_t)j * jstep + kn);
      short8 af[MI];
#pragma unroll
      for (int i = 0; i < MI; i++)
        af[i] = *(const short8*)&As[(wm + 16 * i + l16) * 32 + qx];
#pragma unroll
      for (int i = 0; i < MI; i++)
#pragma unroll
        for (int j = 0; j < 4; j++)
          acc[i][j] = __builtin_amdgcn_mfma_f32_16x16x32_bf16(af[i], bw[j], acc[i][j], 0, 0, 0);
#pragma unroll
      for (int j = 0; j < 4; j++) bw[j] = bpf[j];
    }
  }

#pragma unroll
  for (int i = 0; i < MI; i++) {
#pragma unroll
    for (int j = 0; j < 4; j++) {
      const int colg = bn + wn + 16 * j + l16;
      const float bb = gz.bias ? gz.bias[colg] : 0.f;
#pragma unroll
      for (int r = 0; r < 4; r++) {
        const int rowg = bm + wm + 16 * i + quad * 4 + r;
        const float v = (acc[i][j][r] + bb) * gz.scale;
        const ushort_t bo = f2bf(v);
        if (gz.Cb)  gz.Cb[(size_t)rowg * 512 + colg] = bo;
        if (gz.CbT) gz.CbT[(size_t)colg * 512 + rowg] = bo;
      }
    }
  }
}

// ---------------- LayerNorm family (N=512), one wave/row, bf16 preacts ----------------
// mode 0: x = P ; mode 1: x = P + R ; mode 2: x = R + sigmoid(P)*msum
__global__ __launch_bounds__(256) void row_ln(
    const ushort_t* __restrict__ P, const ushort_t* __restrict__ R,
    const ushort_t* __restrict__ cross,
    const float* __restrict__ gamma, const float* __restrict__ beta, int gstride,
    ushort_t* __restrict__ outb, float* __restrict__ outf, int mode, int gelu)
{
  const size_t S2 = (size_t)8192 * 512;
  const int wid = threadIdx.x >> 6, lane = threadIdx.x & 63;
  const int row = blockIdx.x * 4 + wid;
  const int t = row >> 13;
  const float* g  = gamma + t * gstride;
  const float* be = beta + t * gstride;
  const ushort_t* p = P + (size_t)row * 512;
  const ushort_t* ar = nullptr;
  if (mode == 2) ar = cross + (size_t)t * S2 + (size_t)(row & 8191) * 512;
  float v[8], s = 0.f, ss = 0.f;
#pragma unroll
  for (int j = 0; j < 8; j++) {
    const int c = lane + j * 64;
    float x = bf2f(p[c]);
    if (mode == 2) {
      const float sg = 1.f / (1.f + __expf(-x));
      x = bf2f(R[(size_t)row * 512 + c]) + sg * bf2f(ar[c]);
    } else if (mode == 1) {
      x += bf2f(R[(size_t)row * 512 + c]);
    }
    v[j] = x; s += x; ss += x * x;
  }
#pragma unroll
  for (int off = 32; off > 0; off >>= 1) {
    s  += __shfl_xor(s,  off, 64);
    ss += __shfl_xor(ss, off, 64);
  }
  const float mean = s * (1.f / 512.f);
  const float var  = ss * (1.f / 512.f) - mean * mean;
  const float rstd = rsqrtf(var + 1e-5f);
#pragma unroll
  for (int j = 0; j < 8; j++) {
    const int c = lane + j * 64;
    float y = g[c] * ((v[j] - mean) * rstd) + be[c];
    if (gelu) y = 0.5f * y * (1.f + erff(y * 0.70710678118f));
    if (outb) outb[(size_t)row * 512 + c] = f2bf(y);
    else      outf[(size_t)row * 512 + c] = y;
  }
}

// ---------------- merged logit projections: GELU(LN(sigmoid(x)@W + b)); grid (2048,3) ----------------
__global__ __launch_bounds__(256) void lproj3(
    const float* __restrict__ vl, const float* __restrict__ il, const float* __restrict__ tl,
    const float* __restrict__ Wv, const float* __restrict__ bv,
    const float* __restrict__ Wi, const float* __restrict__ bi,
    const float* __restrict__ Wt, const float* __restrict__ bt,
    const float* __restrict__ lp_g, const float* __restrict__ lp_be,
    ushort_t* __restrict__ out)
{
  const int set = blockIdx.y;
  const float* logits = set == 0 ? vl : set == 1 ? il : tl;
  const int F = set == 0 ? 10 : set == 1 ? 6 : 15;
  const float* W    = set == 0 ? Wv : set == 1 ? Wi : Wt;
  const float* bias = set == 0 ? bv : set == 1 ? bi : bt;
  const float* gamma = lp_g + set * 256;
  const float* beta  = lp_be + set * 256;
  ushort_t* o = out + (size_t)set * 8192 * 256;
  const int wid = threadIdx.x >> 6, lane = threadIdx.x & 63;
  const int row = blockIdx.x * 4 + wid;
  float sg[16];
  for (int f = 0; f < F; f++)
    sg[f] = 1.f / (1.f + __expf(-logits[(size_t)row * F + f]));
  float v[4], s = 0.f, ss = 0.f;
#pragma unroll
  for (int j = 0; j < 4; j++) {
    const int c = lane + j * 64;
    float a = bias[c];
    for (int f = 0; f < F; f++) a += sg[f] * W[f * 256 + c];
    v[j] = a; s += a; ss += a * a;
  }
#pragma unroll
  for (int off = 32; off > 0; off >>= 1) {
    s  += __shfl_xor(s,  off, 64);
    ss += __shfl_xor(ss, off, 64);
  }
  const float mean = s * (1.f / 256.f);
  const float var  = ss * (1.f / 256.f) - mean * mean;
  const float rstd = rsqrtf(var + 1e-5f);
#pragma unroll
  for (int j = 0; j < 4; j++) {
    const int c = lane + j * 64;
    float y = gamma[c] * ((v[j] - mean) * rstd) + beta[c];
    y = 0.5f * y * (1.f + erff(y * 0.70710678118f));
    o[(size_t)row * 256 + c] = f2bf(y);
  }
}

// ---------------- prep: all conversions + cb, one launch ----------------
struct PrepArgs {
  const float *vh, *ih, *th;
  const float *mha_in_W, *mha_out_W, *mha_in_b, *mha_out_b;
  const float *hp_W, *gate_W, *fus_W1, *fus_W2;
  ushort_t *xbf, *Wvbf, *hpWt, *gateWt, *fusW1t, *fusW2t, *WoT;
  float *cb;
};

__global__ __launch_bounds__(256) void prep(PrepArgs pa) {
  __shared__ float tsh[32][33];
  const int b = blockIdx.x, tid = threadIdx.x;
  if (b < 24576) {                       // hidden f32 -> bf16
    const int mat = b >> 13, blk = b & 8191;
    const float* src = mat == 0 ? pa.vh : mat == 1 ? pa.ih : pa.th;
    const size_t i = (size_t)blk * 256 + tid;
    const float4 f = ((const float4*)src)[i];
    ushort4 o; o.x = f2bf(f.x); o.y = f2bf(f.y); o.z = f2bf(f.z); o.w = f2bf(f.w);
    ((ushort4*)(pa.xbf + (size_t)mat * 8192 * 1024))[i] = o;
    return;
  }
  if (b < 28672) {                       // Wv slice -> bf16
    const int u = b - 24576, z = u >> 10, blk = u & 1023;
    const int idx = blk * 256 + tid, r = idx >> 9, c = idx & 511;
    pa.Wvbf[(size_t)z * 262144 + idx] =
        f2bf(pa.mha_in_W[(size_t)z * 786432 + (size_t)r * 1536 + 1024 + c]);
    return;
  }
  if (b >= 34176) {                      // cb_z = bv_z @ Wo_z + bo_z
    const int u2 = b - 34176, z = u2 >> 1, part = u2 & 1;
    const int n = part * 256 + tid;
    const float* bv = pa.mha_in_b + z * 1536 + 1024;
    const float* Wo = pa.mha_out_W + (size_t)z * 262144;
    float a = pa.mha_out_b[z * 512 + n];
    for (int k = 0; k < 512; k++) a += bv[k] * Wo[(size_t)k * 512 + n];
    pa.cb[z * 512 + n] = a;
    return;
  }
  // transpose-converts
  const float* tin; ushort_t* tout; int K, N, u; size_t izs, ozs;
  if (b < 30208)      { u = b - 28672; tin = pa.hp_W;      tout = pa.hpWt;   K = 1024; N = 512; izs = 524288; ozs = 524288; }
  else if (b < 31744) { u = b - 30208; tin = pa.gate_W;    tout = pa.gateWt; K = 1024; N = 512; izs = 524288; ozs = 524288; }
  else if (b < 32896) { u = b - 31744; tin = pa.fus_W1;    tout = pa.fusW1t; K = 2304; N = 512; izs = 0;      ozs = 0; }
  else if (b < 33152) { u = b - 32896; tin = pa.fus_W2;    tout = pa.fusW2t; K = 512;  N = 512; izs = 0;      ozs = 0; }
  else                { u = b - 33152; tin = pa.mha_out_W; tout = pa.WoT;    K = 512;  N = 512; izs = 262144; ozs = 262144; }
  const int nbx = N / 32, perz = nbx * (K / 32);
  const int z = u / perz, rem = u % perz, bx = rem % nbx, by = rem / nbx;
  tin += (size_t)z * izs; tout += (size_t)z * ozs;
  const int n0 = bx * 32, k0 = by * 32;
  const int tx = tid & 31, ty = tid >> 5;
#pragma unroll
  for (int r = 0; r < 32; r += 8)
    tsh[ty + r][tx] = tin[(size_t)(k0 + ty + r) * N + n0 + tx];
  __syncthreads();
#pragma unroll
  for (int r = 0; r < 32; r += 8)
    tout[(size_t)(n0 + ty + r) * K + k0 + tx] = f2bf(tsh[tx][ty + r]);
}

// gate folded bias + cross bias sum:
// bias2[t][n] = gate_b[t][n] + 0.5*sum_k (cb[m1]+cb[m2])[k] * gate_W[t][512+k][n]
// cbsum[t][n] = cb[m1][n] + cb[m2][n]
__global__ __launch_bounds__(256) void bias2_k(
    const float* __restrict__ cb, const float* __restrict__ gate_W,
    const float* __restrict__ gate_b, float* __restrict__ out,
    float* __restrict__ out2)
{
  const int t = blockIdx.z;
  const int m1[3] = {1, 1, 2}, m2[3] = {2, 3, 3};
  const float* c1 = cb + m1[t] * 512;
  const float* c2 = cb + m2[t] * 512;
  const float* W = gate_W + (size_t)t * 524288 + (size_t)512 * 512;
  const int n = blockIdx.x * 256 + threadIdx.x;
  float a = gate_b[t * 512 + n];
  for (int k = 0; k < 512; k++) a += 0.5f * (c1[k] + c2[k]) * W[(size_t)k * 512 + n];
  out[t * 512 + n] = a;
  out2[t * 512 + n] = c1[n] + c2[n];
}

extern "C" void kernel_launch(void* const* d_in, const int* in_sizes, int n_in,
                              void* d_out, int out_size, void* d_ws, size_t ws_size,
                              hipStream_t stream)
{
  const float* verb_hidden   = (const float*)d_in[0];
  const float* verb_logits   = (const float*)d_in[1];
  const float* inst_hidden   = (const float*)d_in[2];
  const float* inst_logits   = (const float*)d_in[3];
  const float* target_hidden = (const float*)d_in[4];
  const float* target_logits = (const float*)d_in[5];
  const float* hp_W  = (const float*)d_in[6];
  const float* hp_b  = (const float*)d_in[7];
  const float* hp_g  = (const float*)d_in[8];
  const float* hp_be = (const float*)d_in[9];
  const float* lp_W_verb   = (const float*)d_in[10];
  const float* lp_b_verb   = (const float*)d_in[11];
  const float* lp_W_inst   = (const float*)d_in[12];
  const float* lp_b_inst   = (const float*)d_in[13];
  const float* lp_W_target = (const float*)d_in[14];
  const float* lp_b_target = (const float*)d_in[15];
  const float* lp_g  = (const float*)d_in[16];
  const float* lp_be = (const float*)d_in[17];
  const float* mha_in_W  = (const float*)d_in[18];
  const float* mha_in_b  = (const float*)d_in[19];
  const float* mha_out_W = (const float*)d_in[20];
  const float* mha_out_b = (const float*)d_in[21];
  const float* n1_g  = (const float*)d_in[22];
  const float* n1_be = (const float*)d_in[23];
  const float* n2_g  = (const float*)d_in[24];
  const float* n2_be = (const float*)d_in[25];
  const float* gate_W = (const float*)d_in[26];
  const float* gate_b = (const float*)d_in[27];
  const float* fus_W1 = (const float*)d_in[28];
  const float* fus_b1 = (const float*)d_in[29];
  const float* fus_g1 = (const float*)d_in[30];
  const float* fus_ge1= (const float*)d_in[31];
  const float* fus_W2 = (const float*)d_in[32];
  const float* fus_b2 = (const float*)d_in[33];
  const float* fus_g2 = (const float*)d_in[34];
  const float* fus_ge2= (const float*)d_in[35];

  char* w = (char*)d_ws;
  const size_t S2 = (size_t)8192 * 512;
  const size_t MB = 1024 * 1024;
  // region0 48MB: xbf (L1-L4) -> crossbf (L9-L10, 24MB) -> gbf (L12-L13)
  ushort_t* xbf     = (ushort_t*)(w);
  ushort_t* crossbf = (ushort_t*)(w);
  ushort_t* gbf     = (ushort_t*)(w);
  ushort_t* Pbig    = (ushort_t*)(w + 48 * MB);   // 24 MB bf16 preacts (3 x S2)
  ushort_t* hbf     = (ushort_t*)(w + 72 * MB);   // 24 MB; later fbf
  ushort_t* fbf     = (ushort_t*)(w + 72 * MB);
  ushort_t* ebf     = (ushort_t*)(w + 96 * MB);   // 24 MB
  ushort_t* lbf     = (ushort_t*)(w + 120 * MB);  // 12 MB
  char* wp = w + 132 * MB;
  ushort_t* hpWt    = (ushort_t*)(wp);                 // 3x512x1024 bf16
  ushort_t* gateWt  = (ushort_t*)(wp + 3145728);       // 3x512x1024
  ushort_t* fusW1t  = (ushort_t*)(wp + 6291456);       // 512x2304
  ushort_t* fusW2t  = (ushort_t*)(wp + 8650752);       // 512x512
  ushort_t* WoT     = (ushort_t*)(wp + 9175040);       // 4x512x512
  ushort_t* Wvbf    = (ushort_t*)(wp + 11272192);      // 4x512x512
  ushort_t* CWt     = (ushort_t*)(wp + 13369344);      // 4x512x512 (CW^T)
  ushort_t* CWplain = (ushort_t*)(wp + 15466496);      // 4x512x512 (CW row-major)
  ushort_t* Gt      = (ushort_t*)(wp + 17563648);      // 6x512x512 (0.5*CW_m@Wbot_t, [n][k])
  float*    cb      = (float*)(wp + 20709376);         // 4x512 f32
  float*    bias2   = (float*)(wp + 20717568);         // 3x512 f32
  float*    cbsum   = (float*)(wp + 20723712);         // 3x512 f32

  dim3 blk(256);
  const int mods[3][2] = {{1, 2}, {1, 3}, {2, 3}};
  const int srcs[3][2] = {{1, 2}, {0, 2}, {0, 1}};

  // L1: prep
  {
    PrepArgs pa;
    pa.vh = verb_hidden; pa.ih = inst_hidden; pa.th = target_hidden;
    pa.mha_in_W = mha_in_W; pa.mha_out_W = mha_out_W;
    pa.mha_in_b = mha_in_b; pa.mha_out_b = mha_out_b;
    pa.hp_W = hp_W; pa.gate_W = gate_W; pa.fus_W1 = fus_W1; pa.fus_W2 = fus_W2;
    pa.xbf = xbf; pa.Wvbf = Wvbf; pa.hpWt = hpWt; pa.gateWt = gateWt;
    pa.fusW1t = fusW1t; pa.fusW2t = fusW2t; pa.WoT = WoT; pa.cb = cb;
    prep<<<34184, blk, 0, stream>>>(pa);
  }

  // L2: fold1 — CW_z = Wv_z @ Wo_z, write both plain and transposed bf16
  {
    GemmArgs ga{};
    for (int z = 0; z < 4; z++) {
      GemmZ& g = ga.z[z];
      g.Cb = CWplain + (size_t)z * 262144; g.CbT = CWt + (size_t)z * 262144;
      g.scale = 1.f; g.nseg = 1; g.mmax = 4;
      g.seg[0] = {Wvbf + (size_t)z * 262144, WoT + (size_t)z * 262144, 512, 512, 512};
    }
    gemm_bt<128, 2><<<dim3(4, 4, 4), blk, 0, stream>>>(ga);
  }

  // L3: folded gate biases + cross bias sums
  bias2_k<<<dim3(2, 1, 3), blk, 0, stream>>>(cb, gate_W, gate_b, bias2, cbsum);

  // L4: stage A (z=0..2) + fold2 G_{t,u} = 0.5*CW_m@Wbot_t (z=3..8, masked)
  {
    GemmArgs ga{};
    for (int z = 0; z < 3; z++) {
      GemmZ& g = ga.z[z];
      g.Cb = Pbig + (size_t)z * S2; g.bias = hp_b + z * 512;
      g.scale = 1.f; g.nseg = 1; g.mmax = 64;
      g.seg[0] = {xbf + (size_t)z * 8192 * 1024, hpWt + (size_t)z * 524288, 1024, 1024, 1024};
    }
    for (int idx = 0; idx < 6; idx++) {
      const int t = idx >> 1, u = idx & 1, m = mods[t][u];
      GemmZ& g = ga.z[3 + idx];
      g.Cb = Gt + (size_t)idx * 262144; g.scale = 0.5f; g.nseg = 1; g.mmax = 4;
      // A = Wbot_t^T (gateWt cols 512..1023), W = CW_m row-major
      g.seg[0] = {gateWt + (size_t)t * 524288 + 512, CWplain + (size_t)m * 262144, 1024, 512, 512};
    }
    gemm_bt<128, 4><<<dim3(64, 4, 9), blk, 0, stream>>>(ga);
  }

  // L5: merged logit projections
  lproj3<<<dim3(2048, 3), blk, 0, stream>>>(verb_logits, inst_logits, target_logits,
      lp_W_verb, lp_b_verb, lp_W_inst, lp_b_inst, lp_W_target, lp_b_target,
      lp_g, lp_be, lbf);

  // L6: h = GELU(LN(P))
  row_ln<<<6144, blk, 0, stream>>>(Pbig, nullptr, nullptr, hp_g, hp_be, 512,
                                   hbf, nullptr, 0, 1);

  // L7: stage C preact = h @ CW0 + cb0 (M=24576)
  {
    GemmArgs ga{};
    GemmZ& g = ga.z[0];
    g.Cb = Pbig; g.bias = cb; g.scale = 1.f; g.nseg = 1; g.mmax = 192;
    g.seg[0] = {hbf, CWt, 512, 512, 512};
    gemm_bt<128, 7><<<dim3(192, 4, 1), blk, 0, stream>>>(ga);
  }
  // L8: e = LN(h + P)
  row_ln<<<6144, blk, 0, stream>>>(Pbig, hbf, nullptr, n1_g, n1_be, 512,
                                   ebf, nullptr, 1, 0);

  // L9: merged cross-sums msum_t (z=0..2, nseg=2) + gate (z=3..5, nseg=3)
  {
    GemmArgs ga{};
    for (int t = 0; t < 3; t++) {
      GemmZ& g = ga.z[t];
      g.Cb = crossbf + (size_t)t * S2;
      g.bias = cbsum + t * 512; g.scale = 0.5f; g.nseg = 2; g.mmax = 64;
      g.seg[0] = {ebf + (size_t)srcs[t][0] * S2, CWt + (size_t)mods[t][0] * 262144, 512, 512, 512};
      g.seg[1] = {ebf + (size_t)srcs[t][1] * S2, CWt + (size_t)mods[t][1] * 262144, 512, 512, 512};
    }
    for (int t = 0; t < 3; t++) {
      GemmZ& g = ga.z[3 + t];
      g.Cb = Pbig + (size_t)t * S2; g.bias = bias2 + t * 512;
      g.scale = 1.f; g.nseg = 3; g.mmax = 64;
      g.seg[0] = {ebf + (size_t)t * S2,           gateWt + (size_t)t * 524288, 512, 1024, 512};
      g.seg[1] = {ebf + (size_t)srcs[t][0] * S2,  Gt + (size_t)(2 * t) * 262144,     512, 512, 512};
      g.seg[2] = {ebf + (size_t)srcs[t][1] * S2,  Gt + (size_t)(2 * t + 1) * 262144, 512, 512, 512};
    }
    gemm_bt<128, 9><<<dim3(64, 4, 6), blk, 0, stream>>>(ga);
  }

  // L10: f = LN(e + sigmoid(P)*msum)
  row_ln<<<6144, blk, 0, stream>>>(Pbig, ebf, crossbf, n2_g, n2_be, 512,
                                   fbf, nullptr, 2, 0);

  // L11: fus1 preact = [f0,f1,f2,l0,l1,l2] @ fus_W1 + b1 (6 segments)
  {
    GemmArgs ga{};
    GemmZ& g = ga.z[0];
    g.Cb = Pbig; g.bias = fus_b1; g.scale = 1.f; g.nseg = 6; g.mmax = 128;
    g.seg[0] = {fbf,                          fusW1t,        512, 2304, 512};
    g.seg[1] = {fbf + S2,                     fusW1t + 512,  512, 2304, 512};
    g.seg[2] = {fbf + 2 * S2,                 fusW1t + 1024, 512, 2304, 512};
    g.seg[3] = {lbf,                          fusW1t + 1536, 256, 2304, 256};
    g.seg[4] = {lbf + (size_t)8192 * 256,     fusW1t + 1792, 256, 2304, 256};
    g.seg[5] = {lbf + (size_t)2 * 8192 * 256, fusW1t + 2048, 256, 2304, 256};
    gemm_bt<64, 11><<<dim3(128, 4, 1), blk, 0, stream>>>(ga);
  }
  // L12: g = GELU(LN(P))
  row_ln<<<2048, blk, 0, stream>>>(Pbig, nullptr, nullptr, fus_g1, fus_ge1, 0,
                                   gbf, nullptr, 0, 1);
  // L13: fus2 preact
  {
    GemmArgs ga{};
    GemmZ& g = ga.z[0];
    g.Cb = Pbig; g.bias = fus_b2; g.scale = 1.f; g.nseg = 1; g.mmax = 128;
    g.seg[0] = {gbf, fusW2t, 512, 512, 512};
    gemm_bt<64, 13><<<dim3(128, 4, 1), blk, 0, stream>>>(ga);
  }
  // L14: out = LN(P), f32
  row_ln<<<2048, blk, 0, stream>>>(Pbig, nullptr, nullptr, fus_g2, fus_ge2, 0,
                                   nullptr, (float*)d_out, 0, 0);
}

// Round 7
// 633.896 us; speedup vs baseline: 1.3226x; 1.3226x over previous
//
#include <hip/hip_runtime.h>
#include <math.h>

typedef unsigned short ushort_t;
using short8  = __attribute__((ext_vector_type(8))) short;
using floatx4 = __attribute__((ext_vector_type(4))) float;

__device__ __forceinline__ ushort_t f2bf(float f) {
  unsigned u = __builtin_bit_cast(unsigned, f);
  u = (u + 0x7fffu + ((u >> 16) & 1u)) >> 16;
  return (ushort_t)u;
}
__device__ __forceinline__ float bf2f(ushort_t u) {
  unsigned v = ((unsigned)u) << 16;
  return __builtin_bit_cast(float, v);
}

__device__ __forceinline__ void load_lds16(const ushort_t* g, ushort_t* l) {
  __builtin_amdgcn_global_load_lds(
      (const __attribute__((address_space(1))) unsigned int*)g,
      (__attribute__((address_space(3))) unsigned int*)l, 16, 0, 0);
}

// ---------------- segmented batched GEMM (bf16 in, bf16 out) ----------------
// C[M,512] = (sum_s A_s[M,Ks] @ W_s^T + bias) * scale ; W_s stored [512,Ks] bf16
// BK=64: halves barrier+vmcnt(0)-drain events per FLOP vs BK=32 (the measured
// bound of this 2-barrier structure; r2-r5 falsified dbuf/counted-vmcnt/
// conflicts/B-in-reg as levers). A and B both via global_load_lds, XOR bank
// swizzle on 8x16B slots per 128B row (both-sides involution, rule #21):
//   stage: thread tid loads global col 8*((tid&7) ^ ((tid>>3)&7)), linear LDS dest
//   read:  k-slot (quad+4h) found at slot (quad+4h) ^ (l16&7)   -> 2 lanes/slot, free
struct Seg { const ushort_t* A; const ushort_t* W; int lda, ldw, K; };
struct GemmZ {
  ushort_t* Cb;        // row-major [row*512+col] bf16 (may be null)
  ushort_t* CbT;       // transposed [col*512+row] bf16 (may be null; folds only, M=512)
  const float* bias;
  float scale; int nseg; int mmax;   // blocks with blockIdx.x >= mmax exit
  Seg seg[6];
};
struct GemmArgs { GemmZ z[9]; };

template <int BM>
__device__ __forceinline__ void gemm_body(const GemmArgs& ga) {
  const GemmZ& gz = ga.z[blockIdx.z];
  if ((int)blockIdx.x >= gz.mmax) return;
  __shared__ ushort_t As[BM * 64];
  __shared__ ushort_t Bs[128 * 64];
  const int tid = threadIdx.x;
  const int wid = tid >> 6, lane = tid & 63, quad = lane >> 4, l16 = lane & 15;
  const int bm = blockIdx.x * BM, bn = blockIdx.y * 128;
  constexpr int MI = BM / 32;
  const int wm = (wid & 1) * (BM / 2), wn = (wid >> 1) * 64;
  floatx4 acc[MI][4] = {};
  const int srow = tid >> 3;                       // 0..31 (8 threads per 128B row)
  const int scol = ((tid & 7) ^ (srow & 7)) << 3;  // swizzled source col (elems)
  const int x7 = l16 & 7;

  for (int s = 0; s < gz.nseg; s++) {
    const Seg sg = gz.seg[s];
    const ushort_t* aG = sg.A + (size_t)(bm + srow) * sg.lda + scol;
    const ushort_t* bG = sg.W + (size_t)(bn + srow) * sg.ldw + scol;
    for (int k0 = 0; k0 < sg.K; k0 += 64) {
      __syncthreads();
#pragma unroll
      for (int r = 0; r < BM / 32; r++)
        load_lds16(aG + k0 + (size_t)(32 * r) * sg.lda, As + r * 2048 + tid * 8);
#pragma unroll
      for (int r = 0; r < 4; r++)
        load_lds16(bG + k0 + (size_t)(32 * r) * sg.ldw, Bs + r * 2048 + tid * 8);
      __syncthreads();
      short8 bw[4][2];
#pragma unroll
      for (int j = 0; j < 4; j++)
#pragma unroll
        for (int h = 0; h < 2; h++)
          bw[j][h] = *(const short8*)&Bs[(wn + 16 * j + l16) * 64 + (((quad + 4 * h) ^ x7) << 3)];
#pragma unroll
      for (int i = 0; i < MI; i++) {
        const int rb = (wm + 16 * i + l16) * 64;
        short8 a0 = *(const short8*)&As[rb + ((quad ^ x7) << 3)];
        short8 a1 = *(const short8*)&As[rb + (((quad + 4) ^ x7) << 3)];
#pragma unroll
        for (int j = 0; j < 4; j++) {
          acc[i][j] = __builtin_amdgcn_mfma_f32_16x16x32_bf16(a0, bw[j][0], acc[i][j], 0, 0, 0);
          acc[i][j] = __builtin_amdgcn_mfma_f32_16x16x32_bf16(a1, bw[j][1], acc[i][j], 0, 0, 0);
        }
      }
    }
  }

#pragma unroll
  for (int i = 0; i < MI; i++) {
#pragma unroll
    for (int j = 0; j < 4; j++) {
      const int colg = bn + wn + 16 * j + l16;
      const float bb = gz.bias ? gz.bias[colg] : 0.f;
#pragma unroll
      for (int r = 0; r < 4; r++) {
        const int rowg = bm + wm + 16 * i + quad * 4 + r;
        const float v = (acc[i][j][r] + bb) * gz.scale;
        const ushort_t bo = f2bf(v);
        if (gz.Cb)  gz.Cb[(size_t)rowg * 512 + colg] = bo;
        if (gz.CbT) gz.CbT[(size_t)colg * 512 + rowg] = bo;
      }
    }
  }
}

// Distinct kernel symbols per launch site (per-site rocprof visibility).
__global__ __launch_bounds__(256) void gemm_L2(GemmArgs ga)  { gemm_body<128>(ga); }
__global__ __launch_bounds__(256) void gemm_L4(GemmArgs ga)  { gemm_body<128>(ga); }
__global__ __launch_bounds__(256) void gemm_L7(GemmArgs ga)  { gemm_body<128>(ga); }
__global__ __launch_bounds__(256) void gemm_L9(GemmArgs ga)  { gemm_body<128>(ga); }
__global__ __launch_bounds__(256) void gemm_L11(GemmArgs ga) { gemm_body<64>(ga); }
__global__ __launch_bounds__(256) void gemm_L13(GemmArgs ga) { gemm_body<64>(ga); }

// ---------------- LayerNorm family (N=512), one wave/row, bf16 preacts ----------------
// mode 0: x = P ; mode 1: x = P + R ; mode 2: x = R + sigmoid(P)*msum
__global__ __launch_bounds__(256) void row_ln(
    const ushort_t* __restrict__ P, const ushort_t* __restrict__ R,
    const ushort_t* __restrict__ cross,
    const float* __restrict__ gamma, const float* __restrict__ beta, int gstride,
    ushort_t* __restrict__ outb, float* __restrict__ outf, int mode, int gelu)
{
  const size_t S2 = (size_t)8192 * 512;
  const int wid = threadIdx.x >> 6, lane = threadIdx.x & 63;
  const int row = blockIdx.x * 4 + wid;
  const int t = row >> 13;
  const float* g  = gamma + t * gstride;
  const float* be = beta + t * gstride;
  const ushort_t* p = P + (size_t)row * 512;
  const ushort_t* ar = nullptr;
  if (mode == 2) ar = cross + (size_t)t * S2 + (size_t)(row & 8191) * 512;
  float v[8], s = 0.f, ss = 0.f;
#pragma unroll
  for (int j = 0; j < 8; j++) {
    const int c = lane + j * 64;
    float x = bf2f(p[c]);
    if (mode == 2) {
      const float sg = 1.f / (1.f + __expf(-x));
      x = bf2f(R[(size_t)row * 512 + c]) + sg * bf2f(ar[c]);
    } else if (mode == 1) {
      x += bf2f(R[(size_t)row * 512 + c]);
    }
    v[j] = x; s += x; ss += x * x;
  }
#pragma unroll
  for (int off = 32; off > 0; off >>= 1) {
    s  += __shfl_xor(s,  off, 64);
    ss += __shfl_xor(ss, off, 64);
  }
  const float mean = s * (1.f / 512.f);
  const float var  = ss * (1.f / 512.f) - mean * mean;
  const float rstd = rsqrtf(var + 1e-5f);
#pragma unroll
  for (int j = 0; j < 8; j++) {
    const int c = lane + j * 64;
    float y = g[c] * ((v[j] - mean) * rstd) + be[c];
    if (gelu) y = 0.5f * y * (1.f + erff(y * 0.70710678118f));
    if (outb) outb[(size_t)row * 512 + c] = f2bf(y);
    else      outf[(size_t)row * 512 + c] = y;
  }
}

// ---------------- merged logit projections: GELU(LN(sigmoid(x)@W + b)); grid (2048,3) ----------------
__global__ __launch_bounds__(256) void lproj3(
    const float* __restrict__ vl, const float* __restrict__ il, const float* __restrict__ tl,
    const float* __restrict__ Wv, const float* __restrict__ bv,
    const float* __restrict__ Wi, const float* __restrict__ bi,
    const float* __restrict__ Wt, const float* __restrict__ bt,
    const float* __restrict__ lp_g, const float* __restrict__ lp_be,
    ushort_t* __restrict__ out)
{
  const int set = blockIdx.y;
  const float* logits = set == 0 ? vl : set == 1 ? il : tl;
  const int F = set == 0 ? 10 : set == 1 ? 6 : 15;
  const float* W    = set == 0 ? Wv : set == 1 ? Wi : Wt;
  const float* bias = set == 0 ? bv : set == 1 ? bi : bt;
  const float* gamma = lp_g + set * 256;
  const float* beta  = lp_be + set * 256;
  ushort_t* o = out + (size_t)set * 8192 * 256;
  const int wid = threadIdx.x >> 6, lane = threadIdx.x & 63;
  const int row = blockIdx.x * 4 + wid;
  float sg[16];
  for (int f = 0; f < F; f++)
    sg[f] = 1.f / (1.f + __expf(-logits[(size_t)row * F + f]));
  float v[4], s = 0.f, ss = 0.f;
#pragma unroll
  for (int j = 0; j < 4; j++) {
    const int c = lane + j * 64;
    float a = bias[c];
    for (int f = 0; f < F; f++) a += sg[f] * W[f * 256 + c];
    v[j] = a; s += a; ss += a * a;
  }
#pragma unroll
  for (int off = 32; off > 0; off >>= 1) {
    s  += __shfl_xor(s,  off, 64);
    ss += __shfl_xor(ss, off, 64);
  }
  const float mean = s * (1.f / 256.f);
  const float var  = ss * (1.f / 256.f) - mean * mean;
  const float rstd = rsqrtf(var + 1e-5f);
#pragma unroll
  for (int j = 0; j < 4; j++) {
    const int c = lane + j * 64;
    float y = gamma[c] * ((v[j] - mean) * rstd) + beta[c];
    y = 0.5f * y * (1.f + erff(y * 0.70710678118f));
    o[(size_t)row * 256 + c] = f2bf(y);
  }
}

// ---------------- prep: all conversions + cb, one launch ----------------
struct PrepArgs {
  const float *vh, *ih, *th;
  const float *mha_in_W, *mha_out_W, *mha_in_b, *mha_out_b;
  const float *hp_W, *gate_W, *fus_W1, *fus_W2;
  ushort_t *xbf, *Wvbf, *hpWt, *gateWt, *fusW1t, *fusW2t, *WoT;
  float *cb;
};

__global__ __launch_bounds__(256) void prep(PrepArgs pa) {
  __shared__ float tsh[32][33];
  const int b = blockIdx.x, tid = threadIdx.x;
  if (b < 24576) {                       // hidden f32 -> bf16
    const int mat = b >> 13, blk = b & 8191;
    const float* src = mat == 0 ? pa.vh : mat == 1 ? pa.ih : pa.th;
    const size_t i = (size_t)blk * 256 + tid;
    const float4 f = ((const float4*)src)[i];
    ushort4 o; o.x = f2bf(f.x); o.y = f2bf(f.y); o.z = f2bf(f.z); o.w = f2bf(f.w);
    ((ushort4*)(pa.xbf + (size_t)mat * 8192 * 1024))[i] = o;
    return;
  }
  if (b < 28672) {                       // Wv slice -> bf16
    const int u = b - 24576, z = u >> 10, blk = u & 1023;
    const int idx = blk * 256 + tid, r = idx >> 9, c = idx & 511;
    pa.Wvbf[(size_t)z * 262144 + idx] =
        f2bf(pa.mha_in_W[(size_t)z * 786432 + (size_t)r * 1536 + 1024 + c]);
    return;
  }
  if (b >= 34176) {                      // cb_z = bv_z @ Wo_z + bo_z
    const int u2 = b - 34176, z = u2 >> 1, part = u2 & 1;
    const int n = part * 256 + tid;
    const float* bv = pa.mha_in_b + z * 1536 + 1024;
    const float* Wo = pa.mha_out_W + (size_t)z * 262144;
    float a = pa.mha_out_b[z * 512 + n];
    for (int k = 0; k < 512; k++) a += bv[k] * Wo[(size_t)k * 512 + n];
    pa.cb[z * 512 + n] = a;
    return;
  }
  // transpose-converts
  const float* tin; ushort_t* tout; int K, N, u; size_t izs, ozs;
  if (b < 30208)      { u = b - 28672; tin = pa.hp_W;      tout = pa.hpWt;   K = 1024; N = 512; izs = 524288; ozs = 524288; }
  else if (b < 31744) { u = b - 30208; tin = pa.gate_W;    tout = pa.gateWt; K = 1024; N = 512; izs = 524288; ozs = 524288; }
  else if (b < 32896) { u = b - 31744; tin = pa.fus_W1;    tout = pa.fusW1t; K = 2304; N = 512; izs = 0;      ozs = 0; }
  else if (b < 33152) { u = b - 32896; tin = pa.fus_W2;    tout = pa.fusW2t; K = 512;  N = 512; izs = 0;      ozs = 0; }
  else                { u = b - 33152; tin = pa.mha_out_W; tout = pa.WoT;    K = 512;  N = 512; izs = 262144; ozs = 262144; }
  const int nbx = N / 32, perz = nbx * (K / 32);
  const int z = u / perz, rem = u % perz, bx = rem % nbx, by = rem / nbx;
  tin += (size_t)z * izs; tout += (size_t)z * ozs;
  const int n0 = bx * 32, k0 = by * 32;
  const int tx = tid & 31, ty = tid >> 5;
#pragma unroll
  for (int r = 0; r < 32; r += 8)
    tsh[ty + r][tx] = tin[(size_t)(k0 + ty + r) * N + n0 + tx];
  __syncthreads();
#pragma unroll
  for (int r = 0; r < 32; r += 8)
    tout[(size_t)(n0 + ty + r) * K + k0 + tx] = f2bf(tsh[tx][ty + r]);
}

// gate folded bias + cross bias sum:
// bias2[t][n] = gate_b[t][n] + 0.5*sum_k (cb[m1]+cb[m2])[k] * gate_W[t][512+k][n]
// cbsum[t][n] = cb[m1][n] + cb[m2][n]
__global__ __launch_bounds__(256) void bias2_k(
    const float* __restrict__ cb, const float* __restrict__ gate_W,
    const float* __restrict__ gate_b, float* __restrict__ out,
    float* __restrict__ out2)
{
  const int t = blockIdx.z;
  const int m1[3] = {1, 1, 2}, m2[3] = {2, 3, 3};
  const float* c1 = cb + m1[t] * 512;
  const float* c2 = cb + m2[t] * 512;
  const float* W = gate_W + (size_t)t * 524288 + (size_t)512 * 512;
  const int n = blockIdx.x * 256 + threadIdx.x;
  float a = gate_b[t * 512 + n];
  for (int k = 0; k < 512; k++) a += 0.5f * (c1[k] + c2[k]) * W[(size_t)k * 512 + n];
  out[t * 512 + n] = a;
  out2[t * 512 + n] = c1[n] + c2[n];
}

extern "C" void kernel_launch(void* const* d_in, const int* in_sizes, int n_in,
                              void* d_out, int out_size, void* d_ws, size_t ws_size,
                              hipStream_t stream)
{
  const float* verb_hidden   = (const float*)d_in[0];
  const float* verb_logits   = (const float*)d_in[1];
  const float* inst_hidden   = (const float*)d_in[2];
  const float* inst_logits   = (const float*)d_in[3];
  const float* target_hidden = (const float*)d_in[4];
  const float* target_logits = (const float*)d_in[5];
  const float* hp_W  = (const float*)d_in[6];
  const float* hp_b  = (const float*)d_in[7];
  const float* hp_g  = (const float*)d_in[8];
  const float* hp_be = (const float*)d_in[9];
  const float* lp_W_verb   = (const float*)d_in[10];
  const float* lp_b_verb   = (const float*)d_in[11];
  const float* lp_W_inst   = (const float*)d_in[12];
  const float* lp_b_inst   = (const float*)d_in[13];
  const float* lp_W_target = (const float*)d_in[14];
  const float* lp_b_target = (const float*)d_in[15];
  const float* lp_g  = (const float*)d_in[16];
  const float* lp_be = (const float*)d_in[17];
  const float* mha_in_W  = (const float*)d_in[18];
  const float* mha_in_b  = (const float*)d_in[19];
  const float* mha_out_W = (const float*)d_in[20];
  const float* mha_out_b = (const float*)d_in[21];
  const float* n1_g  = (const float*)d_in[22];
  const float* n1_be = (const float*)d_in[23];
  const float* n2_g  = (const float*)d_in[24];
  const float* n2_be = (const float*)d_in[25];
  const float* gate_W = (const float*)d_in[26];
  const float* gate_b = (const float*)d_in[27];
  const float* fus_W1 = (const float*)d_in[28];
  const float* fus_b1 = (const float*)d_in[29];
  const float* fus_g1 = (const float*)d_in[30];
  const float* fus_ge1= (const float*)d_in[31];
  const float* fus_W2 = (const float*)d_in[32];
  const float* fus_b2 = (const float*)d_in[33];
  const float* fus_g2 = (const float*)d_in[34];
  const float* fus_ge2= (const float*)d_in[35];

  char* w = (char*)d_ws;
  const size_t S2 = (size_t)8192 * 512;
  const size_t MB = 1024 * 1024;
  // region0 48MB: xbf (L1-L4) -> crossbf (L9-L10, 24MB) -> gbf (L12-L13)
  ushort_t* xbf     = (ushort_t*)(w);
  ushort_t* crossbf = (ushort_t*)(w);
  ushort_t* gbf     = (ushort_t*)(w);
  ushort_t* Pbig    = (ushort_t*)(w + 48 * MB);   // 24 MB bf16 preacts (3 x S2)
  ushort_t* hbf     = (ushort_t*)(w + 72 * MB);   // 24 MB; later fbf
  ushort_t* fbf     = (ushort_t*)(w + 72 * MB);
  ushort_t* ebf     = (ushort_t*)(w + 96 * MB);   // 24 MB
  ushort_t* lbf     = (ushort_t*)(w + 120 * MB);  // 12 MB
  char* wp = w + 132 * MB;
  ushort_t* hpWt    = (ushort_t*)(wp);                 // 3x512x1024 bf16
  ushort_t* gateWt  = (ushort_t*)(wp + 3145728);       // 3x512x1024
  ushort_t* fusW1t  = (ushort_t*)(wp + 6291456);       // 512x2304
  ushort_t* fusW2t  = (ushort_t*)(wp + 8650752);       // 512x512
  ushort_t* WoT     = (ushort_t*)(wp + 9175040);       // 4x512x512
  ushort_t* Wvbf    = (ushort_t*)(wp + 11272192);      // 4x512x512
  ushort_t* CWt     = (ushort_t*)(wp + 13369344);      // 4x512x512 (CW^T)
  ushort_t* CWplain = (ushort_t*)(wp + 15466496);      // 4x512x512 (CW row-major)
  ushort_t* Gt      = (ushort_t*)(wp + 17563648);      // 6x512x512 (0.5*CW_m@Wbot_t, [n][k])
  float*    cb      = (float*)(wp + 20709376);         // 4x512 f32
  float*    bias2   = (float*)(wp + 20717568);         // 3x512 f32
  float*    cbsum   = (float*)(wp + 20723712);         // 3x512 f32

  dim3 blk(256);
  const int mods[3][2] = {{1, 2}, {1, 3}, {2, 3}};
  const int srcs[3][2] = {{1, 2}, {0, 2}, {0, 1}};

  // L1: prep
  {
    PrepArgs pa;
    pa.vh = verb_hidden; pa.ih = inst_hidden; pa.th = target_hidden;
    pa.mha_in_W = mha_in_W; pa.mha_out_W = mha_out_W;
    pa.mha_in_b = mha_in_b; pa.mha_out_b = mha_out_b;
    pa.hp_W = hp_W; pa.gate_W = gate_W; pa.fus_W1 = fus_W1; pa.fus_W2 = fus_W2;
    pa.xbf = xbf; pa.Wvbf = Wvbf; pa.hpWt = hpWt; pa.gateWt = gateWt;
    pa.fusW1t = fusW1t; pa.fusW2t = fusW2t; pa.WoT = WoT; pa.cb = cb;
    prep<<<34184, blk, 0, stream>>>(pa);
  }

  // L2: fold1 — CW_z = Wv_z @ Wo_z, write both plain and transposed bf16
  {
    GemmArgs ga{};
    for (int z = 0; z < 4; z++) {
      GemmZ& g = ga.z[z];
      g.Cb = CWplain + (size_t)z * 262144; g.CbT = CWt + (size_t)z * 262144;
      g.scale = 1.f; g.nseg = 1; g.mmax = 4;
      g.seg[0] = {Wvbf + (size_t)z * 262144, WoT + (size_t)z * 262144, 512, 512, 512};
    }
    gemm_L2<<<dim3(4, 4, 4), blk, 0, stream>>>(ga);
  }

  // L3: folded gate biases + cross bias sums
  bias2_k<<<dim3(2, 1, 3), blk, 0, stream>>>(cb, gate_W, gate_b, bias2, cbsum);

  // L4: stage A (z=0..2) + fold2 G_{t,u} = 0.5*CW_m@Wbot_t (z=3..8, masked)
  {
    GemmArgs ga{};
    for (int z = 0; z < 3; z++) {
      GemmZ& g = ga.z[z];
      g.Cb = Pbig + (size_t)z * S2; g.bias = hp_b + z * 512;
      g.scale = 1.f; g.nseg = 1; g.mmax = 64;
      g.seg[0] = {xbf + (size_t)z * 8192 * 1024, hpWt + (size_t)z * 524288, 1024, 1024, 1024};
    }
    for (int idx = 0; idx < 6; idx++) {
      const int t = idx >> 1, u = idx & 1, m = mods[t][u];
      GemmZ& g = ga.z[3 + idx];
      g.Cb = Gt + (size_t)idx * 262144; g.scale = 0.5f; g.nseg = 1; g.mmax = 4;
      // A = Wbot_t^T (gateWt cols 512..1023), W = CW_m row-major
      g.seg[0] = {gateWt + (size_t)t * 524288 + 512, CWplain + (size_t)m * 262144, 1024, 512, 512};
    }
    gemm_L4<<<dim3(64, 4, 9), blk, 0, stream>>>(ga);
  }

  // L5: merged logit projections
  lproj3<<<dim3(2048, 3), blk, 0, stream>>>(verb_logits, inst_logits, target_logits,
      lp_W_verb, lp_b_verb, lp_W_inst, lp_b_inst, lp_W_target, lp_b_target,
      lp_g, lp_be, lbf);

  // L6: h = GELU(LN(P))
  row_ln<<<6144, blk, 0, stream>>>(Pbig, nullptr, nullptr, hp_g, hp_be, 512,
                                   hbf, nullptr, 0, 1);

  // L7: stage C preact = h @ CW0 + cb0 (M=24576)
  {
    GemmArgs ga{};
    GemmZ& g = ga.z[0];
    g.Cb = Pbig; g.bias = cb; g.scale = 1.f; g.nseg = 1; g.mmax = 192;
    g.seg[0] = {hbf, CWt, 512, 512, 512};
    gemm_L7<<<dim3(192, 4, 1), blk, 0, stream>>>(ga);
  }
  // L8: e = LN(h + P)
  row_ln<<<6144, blk, 0, stream>>>(Pbig, hbf, nullptr, n1_g, n1_be, 512,
                                   ebf, nullptr, 1, 0);

  // L9: merged cross-sums msum_t (z=0..2, nseg=2) + gate (z=3..5, nseg=3)
  {
    GemmArgs ga{};
    for (int t = 0; t < 3; t++) {
      GemmZ& g = ga.z[t];
      g.Cb = crossbf + (size_t)t * S2;
      g.bias = cbsum + t * 512; g.scale = 0.5f; g.nseg = 2; g.mmax = 64;
      g.seg[0] = {ebf + (size_t)srcs[t][0] * S2, CWt + (size_t)mods[t][0] * 262144, 512, 512, 512};
      g.seg[1] = {ebf + (size_t)srcs[t][1] * S2, CWt + (size_t)mods[t][1] * 262144, 512, 512, 512};
    }
    for (int t = 0; t < 3; t++) {
      GemmZ& g = ga.z[3 + t];
      g.Cb = Pbig + (size_t)t * S2; g.bias = bias2 + t * 512;
      g.scale = 1.f; g.nseg = 3; g.mmax = 64;
      g.seg[0] = {ebf + (size_t)t * S2,           gateWt + (size_t)t * 524288, 512, 1024, 512};
      g.seg[1] = {ebf + (size_t)srcs[t][0] * S2,  Gt + (size_t)(2 * t) * 262144,     512, 512, 512};
      g.seg[2] = {ebf + (size_t)srcs[t][1] * S2,  Gt + (size_t)(2 * t + 1) * 262144, 512, 512, 512};
    }
    gemm_L9<<<dim3(64, 4, 6), blk, 0, stream>>>(ga);
  }

  // L10: f = LN(e + sigmoid(P)*msum)
  row_ln<<<6144, blk, 0, stream>>>(Pbig, ebf, crossbf, n2_g, n2_be, 512,
                                   fbf, nullptr, 2, 0);

  // L11: fus1 preact = [f0,f1,f2,l0,l1,l2] @ fus_W1 + b1 (6 segments)
  {
    GemmArgs ga{};
    GemmZ& g = ga.z[0];
    g.Cb = Pbig; g.bias = fus_b1; g.scale = 1.f; g.nseg = 6; g.mmax = 128;
    g.seg[0] = {fbf,                          fusW1t,        512, 2304, 512};
    g.seg[1] = {fbf + S2,                     fusW1t + 512,  512, 2304, 512};
    g.seg[2] = {fbf + 2 * S2,                 fusW1t + 1024, 512, 2304, 512};
    g.seg[3] = {lbf,                          fusW1t + 1536, 256, 2304, 256};
    g.seg[4] = {lbf + (size_t)8192 * 256,     fusW1t + 1792, 256, 2304, 256};
    g.seg[5] = {lbf + (size_t)2 * 8192 * 256, fusW1t + 2048, 256, 2304, 256};
    gemm_L11<<<dim3(128, 4, 1), blk, 0, stream>>>(ga);
  }
  // L12: g = GELU(LN(P))
  row_ln<<<2048, blk, 0, stream>>>(Pbig, nullptr, nullptr, fus_g1, fus_ge1, 0,
                                   gbf, nullptr, 0, 1);
  // L13: fus2 preact
  {
    GemmArgs ga{};
    GemmZ& g = ga.z[0];
    g.Cb = Pbig; g.bias = fus_b2; g.scale = 1.f; g.nseg = 1; g.mmax = 128;
    g.seg[0] = {gbf, fusW2t, 512, 512, 512};
    gemm_L13<<<dim3(128, 4, 1), blk, 0, stream>>>(ga);
  }
  // L14: out = LN(P), f32
  row_ln<<<2048, blk, 0, stream>>>(Pbig, nullptr, nullptr, fus_g2, fus_ge2, 0,
                                   nullptr, (float*)d_out, 0, 0);
}

// Round 8
// 618.767 us; speedup vs baseline: 1.3549x; 1.0245x over previous
//
#include <hip/hip_runtime.h>
#include <math.h>

typedef unsigned short ushort_t;
using short8  = __attribute__((ext_vector_type(8))) short;
using floatx4 = __attribute__((ext_vector_type(4))) float;

__device__ __forceinline__ ushort_t f2bf(float f) {
  unsigned u = __builtin_bit_cast(unsigned, f);
  u = (u + 0x7fffu + ((u >> 16) & 1u)) >> 16;
  return (ushort_t)u;
}
__device__ __forceinline__ float bf2f(ushort_t u) {
  unsigned v = ((unsigned)u) << 16;
  return __builtin_bit_cast(float, v);
}

__device__ __forceinline__ void load_lds16(const ushort_t* g, ushort_t* l) {
  __builtin_amdgcn_global_load_lds(
      (const __attribute__((address_space(1))) unsigned int*)g,
      (__attribute__((address_space(3))) unsigned int*)l, 16, 0, 0);
}

// ---------------- segmented batched GEMM (bf16 in, bf16 out) ----------------
// C[M,512] = (sum_s A_s[M,Ks] @ W_s^T + bias) * scale ; W_s stored [512,Ks] bf16
// BK=128: barrier+vmcnt(0)-drain events per FLOP halved again vs BK=64 (the
// validated lever: r7 BK 32->64 gave -13.5% on the hot GEMM; dbuf/counted-
// vmcnt/conflict-fix/B-in-reg all null on this 2-barrier structure, r2-r5).
// XOR bank swizzle, 16x16B slots per 256B row (both-sides involution, #21):
//   stage: thread tid loads k-chunk (tid&15)^(tid>>4) (row&15 == tid>>4, const
//          across issues), linear LDS dest (global_load_lds requirement)
//   read:  k-chunk kw*4+quad found at slot (kw*4+quad)^l16 (row&15 == l16)
//   -> every bank-quad serves exactly 2 lanes per wave read: conflict-free.
struct Seg { const ushort_t* A; const ushort_t* W; int lda, ldw, K; };
struct GemmZ {
  ushort_t* Cb;        // row-major [row*512+col] bf16 (may be null)
  ushort_t* CbT;       // transposed [col*512+row] bf16 (may be null; folds only, M=512)
  const float* bias;
  float scale; int nseg; int mmax;   // blocks with blockIdx.x >= mmax exit
  Seg seg[6];
};
struct GemmArgs { GemmZ z[9]; };

template <int BM>
__device__ __forceinline__ void gemm_body(const GemmArgs& ga) {
  const GemmZ& gz = ga.z[blockIdx.z];
  if ((int)blockIdx.x >= gz.mmax) return;
  __shared__ ushort_t As[BM * 128];
  __shared__ ushort_t Bs[128 * 128];
  const int tid = threadIdx.x;
  const int wid = tid >> 6, lane = tid & 63, quad = lane >> 4, l16 = lane & 15;
  const int bm = blockIdx.x * BM, bn = blockIdx.y * 128;
  constexpr int MI = BM / 32;
  const int wm = (wid & 1) * (BM / 2), wn = (wid >> 1) * 64;
  floatx4 acc[MI][4] = {};
  const int srow = tid >> 4;                        // 0..15 (16 threads per 256B row)
  const int scol = ((tid & 15) ^ srow) << 3;        // swizzled source col (elems)

  for (int s = 0; s < gz.nseg; s++) {
    const Seg sg = gz.seg[s];
    const ushort_t* aG = sg.A + (size_t)(bm + srow) * sg.lda + scol;
    const ushort_t* bG = sg.W + (size_t)(bn + srow) * sg.ldw + scol;
    for (int k0 = 0; k0 < sg.K; k0 += 128) {
      __syncthreads();
#pragma unroll
      for (int r = 0; r < BM / 16; r++)
        load_lds16(aG + k0 + (size_t)(16 * r) * sg.lda, As + r * 2048 + tid * 8);
#pragma unroll
      for (int r = 0; r < 8; r++)
        load_lds16(bG + k0 + (size_t)(16 * r) * sg.ldw, Bs + r * 2048 + tid * 8);
      __syncthreads();
#pragma unroll
      for (int kw = 0; kw < 4; kw++) {
        const int sl = ((kw * 4 + quad) ^ l16) << 3;
        short8 bw[4];
#pragma unroll
        for (int j = 0; j < 4; j++)
          bw[j] = *(const short8*)&Bs[(wn + 16 * j + l16) * 128 + sl];
#pragma unroll
        for (int i = 0; i < MI; i++) {
          short8 af = *(const short8*)&As[(wm + 16 * i + l16) * 128 + sl];
#pragma unroll
          for (int j = 0; j < 4; j++)
            acc[i][j] = __builtin_amdgcn_mfma_f32_16x16x32_bf16(af, bw[j], acc[i][j], 0, 0, 0);
        }
      }
    }
  }

#pragma unroll
  for (int i = 0; i < MI; i++) {
#pragma unroll
    for (int j = 0; j < 4; j++) {
      const int colg = bn + wn + 16 * j + l16;
      const float bb = gz.bias ? gz.bias[colg] : 0.f;
#pragma unroll
      for (int r = 0; r < 4; r++) {
        const int rowg = bm + wm + 16 * i + quad * 4 + r;
        const float v = (acc[i][j][r] + bb) * gz.scale;
        const ushort_t bo = f2bf(v);
        if (gz.Cb)  gz.Cb[(size_t)rowg * 512 + colg] = bo;
        if (gz.CbT) gz.CbT[(size_t)colg * 512 + rowg] = bo;
      }
    }
  }
}

// Distinct kernel symbols per launch site (per-site rocprof visibility).
__global__ __launch_bounds__(256) void gemm_L2(GemmArgs ga)  { gemm_body<128>(ga); }
__global__ __launch_bounds__(256) void gemm_L4(GemmArgs ga)  { gemm_body<128>(ga); }
__global__ __launch_bounds__(256) void gemm_L7(GemmArgs ga)  { gemm_body<128>(ga); }
__global__ __launch_bounds__(256) void gemm_L9(GemmArgs ga)  { gemm_body<128>(ga); }
__global__ __launch_bounds__(256) void gemm_L11(GemmArgs ga) { gemm_body<64>(ga); }
__global__ __launch_bounds__(256) void gemm_L13(GemmArgs ga) { gemm_body<64>(ga); }

// ---------------- LayerNorm family (N=512), one wave/row, bf16 preacts ----------------
// mode 0: x = P ; mode 1: x = P + R ; mode 2: x = R + sigmoid(P)*msum
__global__ __launch_bounds__(256) void row_ln(
    const ushort_t* __restrict__ P, const ushort_t* __restrict__ R,
    const ushort_t* __restrict__ cross,
    const float* __restrict__ gamma, const float* __restrict__ beta, int gstride,
    ushort_t* __restrict__ outb, float* __restrict__ outf, int mode, int gelu)
{
  const size_t S2 = (size_t)8192 * 512;
  const int wid = threadIdx.x >> 6, lane = threadIdx.x & 63;
  const int row = blockIdx.x * 4 + wid;
  const int t = row >> 13;
  const float* g  = gamma + t * gstride;
  const float* be = beta + t * gstride;
  const ushort_t* p = P + (size_t)row * 512;
  const ushort_t* ar = nullptr;
  if (mode == 2) ar = cross + (size_t)t * S2 + (size_t)(row & 8191) * 512;
  float v[8], s = 0.f, ss = 0.f;
#pragma unroll
  for (int j = 0; j < 8; j++) {
    const int c = lane + j * 64;
    float x = bf2f(p[c]);
    if (mode == 2) {
      const float sg = 1.f / (1.f + __expf(-x));
      x = bf2f(R[(size_t)row * 512 + c]) + sg * bf2f(ar[c]);
    } else if (mode == 1) {
      x += bf2f(R[(size_t)row * 512 + c]);
    }
    v[j] = x; s += x; ss += x * x;
  }
#pragma unroll
  for (int off = 32; off > 0; off >>= 1) {
    s  += __shfl_xor(s,  off, 64);
    ss += __shfl_xor(ss, off, 64);
  }
  const float mean = s * (1.f / 512.f);
  const float var  = ss * (1.f / 512.f) - mean * mean;
  const float rstd = rsqrtf(var + 1e-5f);
#pragma unroll
  for (int j = 0; j < 8; j++) {
    const int c = lane + j * 64;
    float y = g[c] * ((v[j] - mean) * rstd) + be[c];
    if (gelu) y = 0.5f * y * (1.f + erff(y * 0.70710678118f));
    if (outb) outb[(size_t)row * 512 + c] = f2bf(y);
    else      outf[(size_t)row * 512 + c] = y;
  }
}

// ---------------- merged logit projections: GELU(LN(sigmoid(x)@W + b)); grid (2048,3) ----------------
__global__ __launch_bounds__(256) void lproj3(
    const float* __restrict__ vl, const float* __restrict__ il, const float* __restrict__ tl,
    const float* __restrict__ Wv, const float* __restrict__ bv,
    const float* __restrict__ Wi, const float* __restrict__ bi,
    const float* __restrict__ Wt, const float* __restrict__ bt,
    const float* __restrict__ lp_g, const float* __restrict__ lp_be,
    ushort_t* __restrict__ out)
{
  const int set = blockIdx.y;
  const float* logits = set == 0 ? vl : set == 1 ? il : tl;
  const int F = set == 0 ? 10 : set == 1 ? 6 : 15;
  const float* W    = set == 0 ? Wv : set == 1 ? Wi : Wt;
  const float* bias = set == 0 ? bv : set == 1 ? bi : bt;
  const float* gamma = lp_g + set * 256;
  const float* beta  = lp_be + set * 256;
  ushort_t* o = out + (size_t)set * 8192 * 256;
  const int wid = threadIdx.x >> 6, lane = threadIdx.x & 63;
  const int row = blockIdx.x * 4 + wid;
  float sg[16];
  for (int f = 0; f < F; f++)
    sg[f] = 1.f / (1.f + __expf(-logits[(size_t)row * F + f]));
  float v[4], s = 0.f, ss = 0.f;
#pragma unroll
  for (int j = 0; j < 4; j++) {
    const int c = lane + j * 64;
    float a = bias[c];
    for (int f = 0; f < F; f++) a += sg[f] * W[f * 256 + c];
    v[j] = a; s += a; ss += a * a;
  }
#pragma unroll
  for (int off = 32; off > 0; off >>= 1) {
    s  += __shfl_xor(s,  off, 64);
    ss += __shfl_xor(ss, off, 64);
  }
  const float mean = s * (1.f / 256.f);
  const float var  = ss * (1.f / 256.f) - mean * mean;
  const float rstd = rsqrtf(var + 1e-5f);
#pragma unroll
  for (int j = 0; j < 4; j++) {
    const int c = lane + j * 64;
    float y = gamma[c] * ((v[j] - mean) * rstd) + beta[c];
    y = 0.5f * y * (1.f + erff(y * 0.70710678118f));
    o[(size_t)row * 256 + c] = f2bf(y);
  }
}

// ---------------- prep: all conversions + cb, one launch ----------------
struct PrepArgs {
  const float *vh, *ih, *th;
  const float *mha_in_W, *mha_out_W, *mha_in_b, *mha_out_b;
  const float *hp_W, *gate_W, *fus_W1, *fus_W2;
  ushort_t *xbf, *Wvbf, *hpWt, *gateWt, *fusW1t, *fusW2t, *WoT;
  float *cb;
};

__global__ __launch_bounds__(256) void prep(PrepArgs pa) {
  __shared__ float tsh[32][33];
  const int b = blockIdx.x, tid = threadIdx.x;
  if (b < 24576) {                       // hidden f32 -> bf16
    const int mat = b >> 13, blk = b & 8191;
    const float* src = mat == 0 ? pa.vh : mat == 1 ? pa.ih : pa.th;
    const size_t i = (size_t)blk * 256 + tid;
    const float4 f = ((const float4*)src)[i];
    ushort4 o; o.x = f2bf(f.x); o.y = f2bf(f.y); o.z = f2bf(f.z); o.w = f2bf(f.w);
    ((ushort4*)(pa.xbf + (size_t)mat * 8192 * 1024))[i] = o;
    return;
  }
  if (b < 28672) {                       // Wv slice -> bf16
    const int u = b - 24576, z = u >> 10, blk = u & 1023;
    const int idx = blk * 256 + tid, r = idx >> 9, c = idx & 511;
    pa.Wvbf[(size_t)z * 262144 + idx] =
        f2bf(pa.mha_in_W[(size_t)z * 786432 + (size_t)r * 1536 + 1024 + c]);
    return;
  }
  if (b >= 34176) {                      // cb_z = bv_z @ Wo_z + bo_z, k-parallel
    const int u2 = b - 34176;            // 0..31: z = u2>>3, 64-output chunk = u2&7
    const int z = u2 >> 3, n0 = (u2 & 7) * 64;
    const int lane = tid & 63, wv = tid >> 6;
    const int o = lane & 15, p = lane >> 4;
    const int n = n0 + wv * 16 + o;
    const float* bv = pa.mha_in_b + z * 1536 + 1024;
    const float* Wo = pa.mha_out_W + (size_t)z * 262144;
    float a = 0.f;
#pragma unroll 4
    for (int kk = 0; kk < 128; kk++) {
      const int k = p * 128 + kk;
      a += bv[k] * Wo[(size_t)k * 512 + n];
    }
    a += __shfl_xor(a, 16, 64);
    a += __shfl_xor(a, 32, 64);
    if (p == 0) pa.cb[z * 512 + n] = a + pa.mha_out_b[z * 512 + n];
    return;
  }
  // transpose-converts
  const float* tin; ushort_t* tout; int K, N, u; size_t izs, ozs;
  if (b < 30208)      { u = b - 28672; tin = pa.hp_W;      tout = pa.hpWt;   K = 1024; N = 512; izs = 524288; ozs = 524288; }
  else if (b < 31744) { u = b - 30208; tin = pa.gate_W;    tout = pa.gateWt; K = 1024; N = 512; izs = 524288; ozs = 524288; }
  else if (b < 32896) { u = b - 31744; tin = pa.fus_W1;    tout = pa.fusW1t; K = 2304; N = 512; izs = 0;      ozs = 0; }
  else if (b < 33152) { u = b - 32896; tin = pa.fus_W2;    tout = pa.fusW2t; K = 512;  N = 512; izs = 0;      ozs = 0; }
  else                { u = b - 33152; tin = pa.mha_out_W; tout = pa.WoT;    K = 512;  N = 512; izs = 262144; ozs = 262144; }
  const int nbx = N / 32, perz = nbx * (K / 32);
  const int z = u / perz, rem = u % perz, bx = rem % nbx, by = rem / nbx;
  tin += (size_t)z * izs; tout += (size_t)z * ozs;
  const int n0 = bx * 32, k0 = by * 32;
  const int tx = tid & 31, ty = tid >> 5;
#pragma unroll
  for (int r = 0; r < 32; r += 8)
    tsh[ty + r][tx] = tin[(size_t)(k0 + ty + r) * N + n0 + tx];
  __syncthreads();
#pragma unroll
  for (int r = 0; r < 32; r += 8)
    tout[(size_t)(n0 + ty + r) * K + k0 + tx] = f2bf(tsh[tx][ty + r]);
}

// gate folded bias + cross bias sum (k-parallel, grid (8,1,3)):
// bias2[t][n] = gate_b[t][n] + 0.5*sum_k (cb[m1]+cb[m2])[k] * gate_W[t][512+k][n]
// cbsum[t][n] = cb[m1][n] + cb[m2][n]
__global__ __launch_bounds__(256) void bias2_k(
    const float* __restrict__ cb, const float* __restrict__ gate_W,
    const float* __restrict__ gate_b, float* __restrict__ out,
    float* __restrict__ out2)
{
  const int t = blockIdx.z;
  const int m1[3] = {1, 1, 2}, m2[3] = {2, 3, 3};
  const float* c1 = cb + m1[t] * 512;
  const float* c2 = cb + m2[t] * 512;
  const float* W = gate_W + (size_t)t * 524288 + (size_t)512 * 512;
  const int tid = threadIdx.x;
  const int lane = tid & 63, wv = tid >> 6;
  const int o = lane & 15, p = lane >> 4;
  const int n = blockIdx.x * 64 + wv * 16 + o;
  float a = 0.f;
#pragma unroll 4
  for (int kk = 0; kk < 128; kk++) {
    const int k = p * 128 + kk;
    a += 0.5f * (c1[k] + c2[k]) * W[(size_t)k * 512 + n];
  }
  a += __shfl_xor(a, 16, 64);
  a += __shfl_xor(a, 32, 64);
  if (p == 0) {
    out[t * 512 + n] = a + gate_b[t * 512 + n];
    out2[t * 512 + n] = c1[n] + c2[n];
  }
}

extern "C" void kernel_launch(void* const* d_in, const int* in_sizes, int n_in,
                              void* d_out, int out_size, void* d_ws, size_t ws_size,
                              hipStream_t stream)
{
  const float* verb_hidden   = (const float*)d_in[0];
  const float* verb_logits   = (const float*)d_in[1];
  const float* inst_hidden   = (const float*)d_in[2];
  const float* inst_logits   = (const float*)d_in[3];
  const float* target_hidden = (const float*)d_in[4];
  const float* target_logits = (const float*)d_in[5];
  const float* hp_W  = (const float*)d_in[6];
  const float* hp_b  = (const float*)d_in[7];
  const float* hp_g  = (const float*)d_in[8];
  const float* hp_be = (const float*)d_in[9];
  const float* lp_W_verb   = (const float*)d_in[10];
  const float* lp_b_verb   = (const float*)d_in[11];
  const float* lp_W_inst   = (const float*)d_in[12];
  const float* lp_b_inst   = (const float*)d_in[13];
  const float* lp_W_target = (const float*)d_in[14];
  const float* lp_b_target = (const float*)d_in[15];
  const float* lp_g  = (const float*)d_in[16];
  const float* lp_be = (const float*)d_in[17];
  const float* mha_in_W  = (const float*)d_in[18];
  const float* mha_in_b  = (const float*)d_in[19];
  const float* mha_out_W = (const float*)d_in[20];
  const float* mha_out_b = (const float*)d_in[21];
  const float* n1_g  = (const float*)d_in[22];
  const float* n1_be = (const float*)d_in[23];
  const float* n2_g  = (const float*)d_in[24];
  const float* n2_be = (const float*)d_in[25];
  const float* gate_W = (const float*)d_in[26];
  const float* gate_b = (const float*)d_in[27];
  const float* fus_W1 = (const float*)d_in[28];
  const float* fus_b1 = (const float*)d_in[29];
  const float* fus_g1 = (const float*)d_in[30];
  const float* fus_ge1= (const float*)d_in[31];
  const float* fus_W2 = (const float*)d_in[32];
  const float* fus_b2 = (const float*)d_in[33];
  const float* fus_g2 = (const float*)d_in[34];
  const float* fus_ge2= (const float*)d_in[35];

  char* w = (char*)d_ws;
  const size_t S2 = (size_t)8192 * 512;
  const size_t MB = 1024 * 1024;
  // region0 48MB: xbf (L1-L4) -> crossbf (L9-L10, 24MB) -> gbf (L12-L13)
  ushort_t* xbf     = (ushort_t*)(w);
  ushort_t* crossbf = (ushort_t*)(w);
  ushort_t* gbf     = (ushort_t*)(w);
  ushort_t* Pbig    = (ushort_t*)(w + 48 * MB);   // 24 MB bf16 preacts (3 x S2)
  ushort_t* hbf     = (ushort_t*)(w + 72 * MB);   // 24 MB; later fbf
  ushort_t* fbf     = (ushort_t*)(w + 72 * MB);
  ushort_t* ebf     = (ushort_t*)(w + 96 * MB);   // 24 MB
  ushort_t* lbf     = (ushort_t*)(w + 120 * MB);  // 12 MB
  char* wp = w + 132 * MB;
  ushort_t* hpWt    = (ushort_t*)(wp);                 // 3x512x1024 bf16
  ushort_t* gateWt  = (ushort_t*)(wp + 3145728);       // 3x512x1024
  ushort_t* fusW1t  = (ushort_t*)(wp + 6291456);       // 512x2304
  ushort_t* fusW2t  = (ushort_t*)(wp + 8650752);       // 512x512
  ushort_t* WoT     = (ushort_t*)(wp + 9175040);       // 4x512x512
  ushort_t* Wvbf    = (ushort_t*)(wp + 11272192);      // 4x512x512
  ushort_t* CWt     = (ushort_t*)(wp + 13369344);      // 4x512x512 (CW^T)
  ushort_t* CWplain = (ushort_t*)(wp + 15466496);      // 4x512x512 (CW row-major)
  ushort_t* Gt      = (ushort_t*)(wp + 17563648);      // 6x512x512 (0.5*CW_m@Wbot_t, [n][k])
  float*    cb      = (float*)(wp + 20709376);         // 4x512 f32
  float*    bias2   = (float*)(wp + 20717568);         // 3x512 f32
  float*    cbsum   = (float*)(wp + 20723712);         // 3x512 f32

  dim3 blk(256);
  const int mods[3][2] = {{1, 2}, {1, 3}, {2, 3}};
  const int srcs[3][2] = {{1, 2}, {0, 2}, {0, 1}};

  // L1: prep (34176 + 32 cb blocks)
  {
    PrepArgs pa;
    pa.vh = verb_hidden; pa.ih = inst_hidden; pa.th = target_hidden;
    pa.mha_in_W = mha_in_W; pa.mha_out_W = mha_out_W;
    pa.mha_in_b = mha_in_b; pa.mha_out_b = mha_out_b;
    pa.hp_W = hp_W; pa.gate_W = gate_W; pa.fus_W1 = fus_W1; pa.fus_W2 = fus_W2;
    pa.xbf = xbf; pa.Wvbf = Wvbf; pa.hpWt = hpWt; pa.gateWt = gateWt;
    pa.fusW1t = fusW1t; pa.fusW2t = fusW2t; pa.WoT = WoT; pa.cb = cb;
    prep<<<34208, blk, 0, stream>>>(pa);
  }

  // L2: fold1 — CW_z = Wv_z @ Wo_z, write both plain and transposed bf16
  {
    GemmArgs ga{};
    for (int z = 0; z < 4; z++) {
      GemmZ& g = ga.z[z];
      g.Cb = CWplain + (size_t)z * 262144; g.CbT = CWt + (size_t)z * 262144;
      g.scale = 1.f; g.nseg = 1; g.mmax = 4;
      g.seg[0] = {Wvbf + (size_t)z * 262144, WoT + (size_t)z * 262144, 512, 512, 512};
    }
    gemm_L2<<<dim3(4, 4, 4), blk, 0, stream>>>(ga);
  }

  // L3: folded gate biases + cross bias sums (k-parallel)
  bias2_k<<<dim3(8, 1, 3), blk, 0, stream>>>(cb, gate_W, gate_b, bias2, cbsum);

  // L4: stage A (z=0..2) + fold2 G_{t,u} = 0.5*CW_m@Wbot_t (z=3..8, masked)
  {
    GemmArgs ga{};
    for (int z = 0; z < 3; z++) {
      GemmZ& g = ga.z[z];
      g.Cb = Pbig + (size_t)z * S2; g.bias = hp_b + z * 512;
      g.scale = 1.f; g.nseg = 1; g.mmax = 64;
      g.seg[0] = {xbf + (size_t)z * 8192 * 1024, hpWt + (size_t)z * 524288, 1024, 1024, 1024};
    }
    for (int idx = 0; idx < 6; idx++) {
      const int t = idx >> 1, u = idx & 1, m = mods[t][u];
      GemmZ& g = ga.z[3 + idx];
      g.Cb = Gt + (size_t)idx * 262144; g.scale = 0.5f; g.nseg = 1; g.mmax = 4;
      // A = Wbot_t^T (gateWt cols 512..1023), W = CW_m row-major
      g.seg[0] = {gateWt + (size_t)t * 524288 + 512, CWplain + (size_t)m * 262144, 1024, 512, 512};
    }
    gemm_L4<<<dim3(64, 4, 9), blk, 0, stream>>>(ga);
  }

  // L5: merged logit projections
  lproj3<<<dim3(2048, 3), blk, 0, stream>>>(verb_logits, inst_logits, target_logits,
      lp_W_verb, lp_b_verb, lp_W_inst, lp_b_inst, lp_W_target, lp_b_target,
      lp_g, lp_be, lbf);

  // L6: h = GELU(LN(P))
  row_ln<<<6144, blk, 0, stream>>>(Pbig, nullptr, nullptr, hp_g, hp_be, 512,
                                   hbf, nullptr, 0, 1);

  // L7: stage C preact = h @ CW0 + cb0 (M=24576)
  {
    GemmArgs ga{};
    GemmZ& g = ga.z[0];
    g.Cb = Pbig; g.bias = cb; g.scale = 1.f; g.nseg = 1; g.mmax = 192;
    g.seg[0] = {hbf, CWt, 512, 512, 512};
    gemm_L7<<<dim3(192, 4, 1), blk, 0, stream>>>(ga);
  }
  // L8: e = LN(h + P)
  row_ln<<<6144, blk, 0, stream>>>(Pbig, hbf, nullptr, n1_g, n1_be, 512,
                                   ebf, nullptr, 1, 0);

  // L9: merged cross-sums msum_t (z=0..2, nseg=2) + gate (z=3..5, nseg=3)
  {
    GemmArgs ga{};
    for (int t = 0; t < 3; t++) {
      GemmZ& g = ga.z[t];
      g.Cb = crossbf + (size_t)t * S2;
      g.bias = cbsum + t * 512; g.scale = 0.5f; g.nseg = 2; g.mmax = 64;
      g.seg[0] = {ebf + (size_t)srcs[t][0] * S2, CWt + (size_t)mods[t][0] * 262144, 512, 512, 512};
      g.seg[1] = {ebf + (size_t)srcs[t][1] * S2, CWt + (size_t)mods[t][1] * 262144, 512, 512, 512};
    }
    for (int t = 0; t < 3; t++) {
      GemmZ& g = ga.z[3 + t];
      g.Cb = Pbig + (size_t)t * S2; g.bias = bias2 + t * 512;
      g.scale = 1.f; g.nseg = 3; g.mmax = 64;
      g.seg[0] = {ebf + (size_t)t * S2,           gateWt + (size_t)t * 524288, 512, 1024, 512};
      g.seg[1] = {ebf + (size_t)srcs[t][0] * S2,  Gt + (size_t)(2 * t) * 262144,     512, 512, 512};
      g.seg[2] = {ebf + (size_t)srcs[t][1] * S2,  Gt + (size_t)(2 * t + 1) * 262144, 512, 512, 512};
    }
    gemm_L9<<<dim3(64, 4, 6), blk, 0, stream>>>(ga);
  }

  // L10: f = LN(e + sigmoid(P)*msum)
  row_ln<<<6144, blk, 0, stream>>>(Pbig, ebf, crossbf, n2_g, n2_be, 512,
                                   fbf, nullptr, 2, 0);

  // L11: fus1 preact = [f0,f1,f2,l0,l1,l2] @ fus_W1 + b1 (6 segments)
  {
    GemmArgs ga{};
    GemmZ& g = ga.z[0];
    g.Cb = Pbig; g.bias = fus_b1; g.scale = 1.f; g.nseg = 6; g.mmax = 128;
    g.seg[0] = {fbf,                          fusW1t,        512, 2304, 512};
    g.seg[1] = {fbf + S2,                     fusW1t + 512,  512, 2304, 512};
    g.seg[2] = {fbf + 2 * S2,                 fusW1t + 1024, 512, 2304, 512};
    g.seg[3] = {lbf,                          fusW1t + 1536, 256, 2304, 256};
    g.seg[4] = {lbf + (size_t)8192 * 256,     fusW1t + 1792, 256, 2304, 256};
    g.seg[5] = {lbf + (size_t)2 * 8192 * 256, fusW1t + 2048, 256, 2304, 256};
    gemm_L11<<<dim3(128, 4, 1), blk, 0, stream>>>(ga);
  }
  // L12: g = GELU(LN(P))
  row_ln<<<2048, blk, 0, stream>>>(Pbig, nullptr, nullptr, fus_g1, fus_ge1, 0,
                                   gbf, nullptr, 0, 1);
  // L13: fus2 preact
  {
    GemmArgs ga{};
    GemmZ& g = ga.z[0];
    g.Cb = Pbig; g.bias = fus_b2; g.scale = 1.f; g.nseg = 1; g.mmax = 128;
    g.seg[0] = {gbf, fusW2t, 512, 512, 512};
    gemm_L13<<<dim3(128, 4, 1), blk, 0, stream>>>(ga);
  }
  // L14: out = LN(P), f32
  row_ln<<<2048, blk, 0, stream>>>(Pbig, nullptr, nullptr, fus_g2, fus_ge2, 0,
                                   nullptr, (float*)d_out, 0, 0);
}

// Round 10
// 544.436 us; speedup vs baseline: 1.5399x; 1.1365x over previous
//
#include <hip/hip_runtime.h>
#include <math.h>

typedef unsigned short ushort_t;
using short8  = __attribute__((ext_vector_type(8))) short;
using floatx4 = __attribute__((ext_vector_type(4))) float;

__device__ __forceinline__ ushort_t f2bf(float f) {
  unsigned u = __builtin_bit_cast(unsigned, f);
  u = (u + 0x7fffu + ((u >> 16) & 1u)) >> 16;
  return (ushort_t)u;
}
__device__ __forceinline__ float bf2f(ushort_t u) {
  unsigned v = ((unsigned)u) << 16;
  return __builtin_bit_cast(float, v);
}

__device__ __forceinline__ void load_lds16(const ushort_t* g, ushort_t* l) {
  __builtin_amdgcn_global_load_lds(
      (const __attribute__((address_space(1))) unsigned int*)g,
      (__attribute__((address_space(3))) unsigned int*)l, 16, 0, 0);
}

// ---------------- segmented batched GEMM (bf16 in, bf16 out) ----------------
// C[M,512] = (sum_s A_s[M,Ks] @ W_s^T + bias) * scale ; W_s stored [512,Ks] bf16
// BK is a PER-SITE knob (r7/r8 measured): 64 for the M=24576/K=512 family
// (L7/L9: 32KB LDS keeps ~2.7 blocks/CU; BK=128's 64KB dropped occupancy to 2
// and regressed L9 +10%), 128 elsewhere (halved barrier/drain events won in
// aggregate). XOR bank swizzle on 16B slots (both-sides involution, rule #21):
//   LDS slot s of row r holds global k-chunk s ^ (r & (TPR-1)); read fetches
//   chunk g at slot g ^ (r & (TPR-1)); linear LDS dest (global_load_lds req).
struct Seg { const ushort_t* A; const ushort_t* W; int lda, ldw, K; };
struct GemmZ {
  ushort_t* Cb;        // row-major [row*512+col] bf16 (may be null)
  ushort_t* CbT;       // transposed [col*512+row] bf16 (may be null; folds only, M=512)
  const float* bias;
  float scale; int nseg; int mmax;   // blocks with blockIdx.x >= mmax exit
  Seg seg[6];
};
struct GemmArgs { GemmZ z[9]; };

template <int BM, int BK>
__device__ __forceinline__ void gemm_body(const GemmArgs& ga) {
  const GemmZ& gz = ga.z[blockIdx.z];
  if ((int)blockIdx.x >= gz.mmax) return;
  __shared__ ushort_t As[BM * BK];
  __shared__ ushort_t Bs[128 * BK];
  constexpr int TPR = BK / 8;        // threads per row (16B chunks per row)
  constexpr int RPC = 2048 / BK;     // rows covered per 256-thread stage issue
  const int tid = threadIdx.x;
  const int wid = tid >> 6, lane = tid & 63, quad = lane >> 4, l16 = lane & 15;
  const int bm = blockIdx.x * BM, bn = blockIdx.y * 128;
  constexpr int MI = BM / 32;
  const int wm = (wid & 1) * (BM / 2), wn = (wid >> 1) * 64;
  floatx4 acc[MI][4] = {};
  const int srow = tid / TPR;
  const int scol = ((tid & (TPR - 1)) ^ (srow & (TPR - 1))) << 3;

  for (int s = 0; s < gz.nseg; s++) {
    const Seg sg = gz.seg[s];
    const ushort_t* aG = sg.A + (size_t)(bm + srow) * sg.lda + scol;
    const ushort_t* bG = sg.W + (size_t)(bn + srow) * sg.ldw + scol;
    for (int k0 = 0; k0 < sg.K; k0 += BK) {
      __syncthreads();
#pragma unroll
      for (int r = 0; r < BM / RPC; r++)
        load_lds16(aG + k0 + (size_t)(RPC * r) * sg.lda, As + r * 2048 + tid * 8);
#pragma unroll
      for (int r = 0; r < 128 / RPC; r++)
        load_lds16(bG + k0 + (size_t)(RPC * r) * sg.ldw, Bs + r * 2048 + tid * 8);
      __syncthreads();
#pragma unroll
      for (int sub = 0; sub < BK / 32; sub++) {
        const int sl = ((sub * 4 + quad) ^ (l16 & (TPR - 1))) << 3;
        short8 bw[4];
#pragma unroll
        for (int j = 0; j < 4; j++)
          bw[j] = *(const short8*)&Bs[(wn + 16 * j + l16) * BK + sl];
#pragma unroll
        for (int i = 0; i < MI; i++) {
          short8 af = *(const short8*)&As[(wm + 16 * i + l16) * BK + sl];
#pragma unroll
          for (int j = 0; j < 4; j++)
            acc[i][j] = __builtin_amdgcn_mfma_f32_16x16x32_bf16(af, bw[j], acc[i][j], 0, 0, 0);
        }
      }
    }
  }

#pragma unroll
  for (int i = 0; i < MI; i++) {
#pragma unroll
    for (int j = 0; j < 4; j++) {
      const int colg = bn + wn + 16 * j + l16;
      const float bb = gz.bias ? gz.bias[colg] : 0.f;
#pragma unroll
      for (int r = 0; r < 4; r++) {
        const int rowg = bm + wm + 16 * i + quad * 4 + r;
        const float v = (acc[i][j][r] + bb) * gz.scale;
        const ushort_t bo = f2bf(v);
        if (gz.Cb)  gz.Cb[(size_t)rowg * 512 + colg] = bo;
        if (gz.CbT) gz.CbT[(size_t)colg * 512 + rowg] = bo;
      }
    }
  }
}

// Distinct kernel symbols per launch site (per-site rocprof visibility).
__global__ __launch_bounds__(256) void gemm_L2(GemmArgs ga)  { gemm_body<128, 128>(ga); }
__global__ __launch_bounds__(256) void gemm_L4(GemmArgs ga)  { gemm_body<128, 128>(ga); }
__global__ __launch_bounds__(256) void gemm_L7(GemmArgs ga)  { gemm_body<128, 64>(ga); }
__global__ __launch_bounds__(256) void gemm_L9(GemmArgs ga)  { gemm_body<128, 64>(ga); }
__global__ __launch_bounds__(256) void gemm_L11(GemmArgs ga) { gemm_body<64, 128>(ga); }
__global__ __launch_bounds__(256) void gemm_L13(GemmArgs ga) { gemm_body<64, 128>(ga); }

// ---------------- LayerNorm family (N=512), one wave/row, bf16 preacts ----------------
// mode 0: x = P ; mode 1: x = P + R ; mode 2: x = R + sigmoid(P)*msum
// Vectorized (G13 / common-mistake #2): lane owns 8 CONTIGUOUS cols -> one
// short8 (16B) load per tensor per lane, one short8 store (was 8x scalar bf16).
__global__ __launch_bounds__(256) void row_ln(
    const ushort_t* __restrict__ P, const ushort_t* __restrict__ R,
    const ushort_t* __restrict__ cross,
    const float* __restrict__ gamma, const float* __restrict__ beta, int gstride,
    ushort_t* __restrict__ outb, float* __restrict__ outf, int mode, int gelu)
{
  const size_t S2 = (size_t)8192 * 512;
  const int wid = threadIdx.x >> 6, lane = threadIdx.x & 63;
  const int row = blockIdx.x * 4 + wid;
  const int t = row >> 13;
  const float* g  = gamma + t * gstride;
  const float* be = beta + t * gstride;
  const int c0 = lane * 8;
  const short8 pv = *(const short8*)&P[(size_t)row * 512 + c0];
  short8 rv = {}, av = {};
  if (mode >= 1) rv = *(const short8*)&R[(size_t)row * 512 + c0];
  if (mode == 2) av = *(const short8*)&cross[(size_t)t * S2 + (size_t)(row & 8191) * 512 + c0];
  float v[8], s = 0.f, ss = 0.f;
#pragma unroll
  for (int j = 0; j < 8; j++) {
    float x = bf2f((ushort_t)pv[j]);
    if (mode == 2) {
      const float sg = 1.f / (1.f + __expf(-x));
      x = bf2f((ushort_t)rv[j]) + sg * bf2f((ushort_t)av[j]);
    } else if (mode == 1) {
      x += bf2f((ushort_t)rv[j]);
    }
    v[j] = x; s += x; ss += x * x;
  }
#pragma unroll
  for (int off = 32; off > 0; off >>= 1) {
    s  += __shfl_xor(s,  off, 64);
    ss += __shfl_xor(ss, off, 64);
  }
  const float mean = s * (1.f / 512.f);
  const float var  = ss * (1.f / 512.f) - mean * mean;
  const float rstd = rsqrtf(var + 1e-5f);
  float gv[8], bv[8];
  *(float4*)&gv[0] = *(const float4*)&g[c0];
  *(float4*)&gv[4] = *(const float4*)&g[c0 + 4];
  *(float4*)&bv[0] = *(const float4*)&be[c0];
  *(float4*)&bv[4] = *(const float4*)&be[c0 + 4];
  float y[8];
#pragma unroll
  for (int j = 0; j < 8; j++) {
    float yy = gv[j] * ((v[j] - mean) * rstd) + bv[j];
    if (gelu) yy = 0.5f * yy * (1.f + erff(yy * 0.70710678118f));
    y[j] = yy;
  }
  if (outb) {
    short8 ov;
#pragma unroll
    for (int j = 0; j < 8; j++) ov[j] = (short)f2bf(y[j]);
    *(short8*)&outb[(size_t)row * 512 + c0] = ov;
  } else {
    *(float4*)&outf[(size_t)row * 512 + c0]     = *(float4*)&y[0];
    *(float4*)&outf[(size_t)row * 512 + c0 + 4] = *(float4*)&y[4];
  }
}

// ---------------- merged logit projections: GELU(LN(sigmoid(x)@W + b)); grid (2048,3) ----------------
__global__ __launch_bounds__(256) void lproj3(
    const float* __restrict__ vl, const float* __restrict__ il, const float* __restrict__ tl,
    const float* __restrict__ Wv, const float* __restrict__ bv,
    const float* __restrict__ Wi, const float* __restrict__ bi,
    const float* __restrict__ Wt, const float* __restrict__ bt,
    const float* __restrict__ lp_g, const float* __restrict__ lp_be,
    ushort_t* __restrict__ out)
{
  const int set = blockIdx.y;
  const float* logits = set == 0 ? vl : set == 1 ? il : tl;
  const int F = set == 0 ? 10 : set == 1 ? 6 : 15;
  const float* W    = set == 0 ? Wv : set == 1 ? Wi : Wt;
  const float* bias = set == 0 ? bv : set == 1 ? bi : bt;
  const float* gamma = lp_g + set * 256;
  const float* beta  = lp_be + set * 256;
  ushort_t* o = out + (size_t)set * 8192 * 256;
  const int wid = threadIdx.x >> 6, lane = threadIdx.x & 63;
  const int row = blockIdx.x * 4 + wid;
  const int c0 = lane * 4;
  float sg[16];
  for (int f = 0; f < F; f++)
    sg[f] = 1.f / (1.f + __expf(-logits[(size_t)row * F + f]));
  float v[4], s = 0.f, ss = 0.f;
  *(float4*)&v[0] = *(const float4*)&bias[c0];
  for (int f = 0; f < F; f++) {
    const float4 w4 = *(const float4*)&W[f * 256 + c0];
#pragma unroll
    for (int j = 0; j < 4; j++) v[j] += sg[f] * w4[j];
  }
#pragma unroll
  for (int j = 0; j < 4; j++) { s += v[j]; ss += v[j] * v[j]; }
#pragma unroll
  for (int off = 32; off > 0; off >>= 1) {
    s  += __shfl_xor(s,  off, 64);
    ss += __shfl_xor(ss, off, 64);
  }
  const float mean = s * (1.f / 256.f);
  const float var  = ss * (1.f / 256.f) - mean * mean;
  const float rstd = rsqrtf(var + 1e-5f);
  const float4 g4 = *(const float4*)&gamma[c0];
  const float4 b4 = *(const float4*)&beta[c0];
  ushort4 ov;
  float y[4];
#pragma unroll
  for (int j = 0; j < 4; j++) {
    float yy = g4[j] * ((v[j] - mean) * rstd) + b4[j];
    yy = 0.5f * yy * (1.f + erff(yy * 0.70710678118f));
    y[j] = yy;
  }
  ov.x = f2bf(y[0]); ov.y = f2bf(y[1]); ov.z = f2bf(y[2]); ov.w = f2bf(y[3]);
  *(ushort4*)&o[(size_t)row * 256 + c0] = ov;
}

// ---------------- prep: all conversions + cb, one launch ----------------
struct PrepArgs {
  const float *vh, *ih, *th;
  const float *mha_in_W, *mha_out_W, *mha_in_b, *mha_out_b;
  const float *hp_W, *gate_W, *fus_W1, *fus_W2;
  ushort_t *xbf, *Wvbf, *hpWt, *gateWt, *fusW1t, *fusW2t, *WoT;
  float *cb;
};

__global__ __launch_bounds__(256) void prep(PrepArgs pa) {
  __shared__ float tsh[32][33];
  const int b = blockIdx.x, tid = threadIdx.x;
  if (b < 24576) {                       // hidden f32 -> bf16
    const int mat = b >> 13, blk = b & 8191;
    const float* src = mat == 0 ? pa.vh : mat == 1 ? pa.ih : pa.th;
    const size_t i = (size_t)blk * 256 + tid;
    const float4 f = ((const float4*)src)[i];
    ushort4 o; o.x = f2bf(f.x); o.y = f2bf(f.y); o.z = f2bf(f.z); o.w = f2bf(f.w);
    ((ushort4*)(pa.xbf + (size_t)mat * 8192 * 1024))[i] = o;
    return;
  }
  if (b < 28672) {                       // Wv slice -> bf16
    const int u = b - 24576, z = u >> 10, blk = u & 1023;
    const int idx = blk * 256 + tid, r = idx >> 9, c = idx & 511;
    pa.Wvbf[(size_t)z * 262144 + idx] =
        f2bf(pa.mha_in_W[(size_t)z * 786432 + (size_t)r * 1536 + 1024 + c]);
    return;
  }
  if (b >= 34176) {                      // cb_z = bv_z @ Wo_z + bo_z, k-parallel
    const int u2 = b - 34176;            // 0..31: z = u2>>3, 64-output chunk = u2&7
    const int z = u2 >> 3, n0 = (u2 & 7) * 64;
    const int lane = tid & 63, wv = tid >> 6;
    const int o = lane & 15, p = lane >> 4;
    const int n = n0 + wv * 16 + o;
    const float* bv = pa.mha_in_b + z * 1536 + 1024;
    const float* Wo = pa.mha_out_W + (size_t)z * 262144;
    float a = 0.f;
#pragma unroll 4
    for (int kk = 0; kk < 128; kk++) {
      const int k = p * 128 + kk;
      a += bv[k] * Wo[(size_t)k * 512 + n];
    }
    a += __shfl_xor(a, 16, 64);
    a += __shfl_xor(a, 32, 64);
    if (p == 0) pa.cb[z * 512 + n] = a + pa.mha_out_b[z * 512 + n];
    return;
  }
  // transpose-converts
  const float* tin; ushort_t* tout; int K, N, u; size_t izs, ozs;
  if (b < 30208)      { u = b - 28672; tin = pa.hp_W;      tout = pa.hpWt;   K = 1024; N = 512; izs = 524288; ozs = 524288; }
  else if (b < 31744) { u = b - 30208; tin = pa.gate_W;    tout = pa.gateWt; K = 1024; N = 512; izs = 524288; ozs = 524288; }
  else if (b < 32896) { u = b - 31744; tin = pa.fus_W1;    tout = pa.fusW1t; K = 2304; N = 512; izs = 0;      ozs = 0; }
  else if (b < 33152) { u = b - 32896; tin = pa.fus_W2;    tout = pa.fusW2t; K = 512;  N = 512; izs = 0;      ozs = 0; }
  else                { u = b - 33152; tin = pa.mha_out_W; tout = pa.WoT;    K = 512;  N = 512; izs = 262144; ozs = 262144; }
  const int nbx = N / 32, perz = nbx * (K / 32);
  const int z = u / perz, rem = u % perz, bx = rem % nbx, by = rem / nbx;
  tin += (size_t)z * izs; tout += (size_t)z * ozs;
  const int n0 = bx * 32, k0 = by * 32;
  const int tx = tid & 31, ty = tid >> 5;
#pragma unroll
  for (int r = 0; r < 32; r += 8)
    tsh[ty + r][tx] = tin[(size_t)(k0 + ty + r) * N + n0 + tx];
  __syncthreads();
#pragma unroll
  for (int r = 0; r < 32; r += 8)
    tout[(size_t)(n0 + ty + r) * K + k0 + tx] = f2bf(tsh[tx][ty + r]);
}

// gate folded bias + cross bias sum (k-parallel, grid (8,1,3)):
// bias2[t][n] = gate_b[t][n] + 0.5*sum_k (cb[m1]+cb[m2])[k] * gate_W[t][512+k][n]
// cbsum[t][n] = cb[m1][n] + cb[m2][n]
__global__ __launch_bounds__(256) void bias2_k(
    const float* __restrict__ cb, const float* __restrict__ gate_W,
    const float* __restrict__ gate_b, float* __restrict__ out,
    float* __restrict__ out2)
{
  const int t = blockIdx.z;
  const int m1[3] = {1, 1, 2}, m2[3] = {2, 3, 3};
  const float* c1 = cb + m1[t] * 512;
  const float* c2 = cb + m2[t] * 512;
  const float* W = gate_W + (size_t)t * 524288 + (size_t)512 * 512;
  const int tid = threadIdx.x;
  const int lane = tid & 63, wv = tid >> 6;
  const int o = lane & 15, p = lane >> 4;
  const int n = blockIdx.x * 64 + wv * 16 + o;
  float a = 0.f;
#pragma unroll 4
  for (int kk = 0; kk < 128; kk++) {
    const int k = p * 128 + kk;
    a += 0.5f * (c1[k] + c2[k]) * W[(size_t)k * 512 + n];
  }
  a += __shfl_xor(a, 16, 64);
  a += __shfl_xor(a, 32, 64);
  if (p == 0) {
    out[t * 512 + n] = a + gate_b[t * 512 + n];
    out2[t * 512 + n] = c1[n] + c2[n];
  }
}

extern "C" void kernel_launch(void* const* d_in, const int* in_sizes, int n_in,
                              void* d_out, int out_size, void* d_ws, size_t ws_size,
                              hipStream_t stream)
{
  const float* verb_hidden   = (const float*)d_in[0];
  const float* verb_logits   = (const float*)d_in[1];
  const float* inst_hidden   = (const float*)d_in[2];
  const float* inst_logits   = (const float*)d_in[3];
  const float* target_hidden = (const float*)d_in[4];
  const float* target_logits = (const float*)d_in[5];
  const float* hp_W  = (const float*)d_in[6];
  const float* hp_b  = (const float*)d_in[7];
  const float* hp_g  = (const float*)d_in[8];
  const float* hp_be = (const float*)d_in[9];
  const float* lp_W_verb   = (const float*)d_in[10];
  const float* lp_b_verb   = (const float*)d_in[11];
  const float* lp_W_inst   = (const float*)d_in[12];
  const float* lp_b_inst   = (const float*)d_in[13];
  const float* lp_W_target = (const float*)d_in[14];
  const float* lp_b_target = (const float*)d_in[15];
  const float* lp_g  = (const float*)d_in[16];
  const float* lp_be = (const float*)d_in[17];
  const float* mha_in_W  = (const float*)d_in[18];
  const float* mha_in_b  = (const float*)d_in[19];
  const float* mha_out_W = (const float*)d_in[20];
  const float* mha_out_b = (const float*)d_in[21];
  const float* n1_g  = (const float*)d_in[22];
  const float* n1_be = (const float*)d_in[23];
  const float* n2_g  = (const float*)d_in[24];
  const float* n2_be = (const float*)d_in[25];
  const float* gate_W = (const float*)d_in[26];
  const float* gate_b = (const float*)d_in[27];
  const float* fus_W1 = (const float*)d_in[28];
  const float* fus_b1 = (const float*)d_in[29];
  const float* fus_g1 = (const float*)d_in[30];
  const float* fus_ge1= (const float*)d_in[31];
  const float* fus_W2 = (const float*)d_in[32];
  const float* fus_b2 = (const float*)d_in[33];
  const float* fus_g2 = (const float*)d_in[34];
  const float* fus_ge2= (const float*)d_in[35];

  char* w = (char*)d_ws;
  const size_t S2 = (size_t)8192 * 512;
  const size_t MB = 1024 * 1024;
  // region0 48MB: xbf (L1-L4) -> crossbf (L9-L10, 24MB) -> gbf (L12-L13)
  ushort_t* xbf     = (ushort_t*)(w);
  ushort_t* crossbf = (ushort_t*)(w);
  ushort_t* gbf     = (ushort_t*)(w);
  ushort_t* Pbig    = (ushort_t*)(w + 48 * MB);   // 24 MB bf16 preacts (3 x S2)
  ushort_t* hbf     = (ushort_t*)(w + 72 * MB);   // 24 MB; later fbf
  ushort_t* fbf     = (ushort_t*)(w + 72 * MB);
  ushort_t* ebf     = (ushort_t*)(w + 96 * MB);   // 24 MB
  ushort_t* lbf     = (ushort_t*)(w + 120 * MB);  // 12 MB
  char* wp = w + 132 * MB;
  ushort_t* hpWt    = (ushort_t*)(wp);                 // 3x512x1024 bf16
  ushort_t* gateWt  = (ushort_t*)(wp + 3145728);       // 3x512x1024
  ushort_t* fusW1t  = (ushort_t*)(wp + 6291456);       // 512x2304
  ushort_t* fusW2t  = (ushort_t*)(wp + 8650752);       // 512x512
  ushort_t* WoT     = (ushort_t*)(wp + 9175040);       // 4x512x512
  ushort_t* Wvbf    = (ushort_t*)(wp + 11272192);      // 4x512x512
  ushort_t* CWt     = (ushort_t*)(wp + 13369344);      // 4x512x512 (CW^T)
  ushort_t* CWplain = (ushort_t*)(wp + 15466496);      // 4x512x512 (CW row-major)
  ushort_t* Gt      = (ushort_t*)(wp + 17563648);      // 6x512x512 (0.5*CW_m@Wbot_t, [n][k])
  float*    cb      = (float*)(wp + 20709376);         // 4x512 f32
  float*    bias2   = (float*)(wp + 20717568);         // 3x512 f32
  float*    cbsum   = (float*)(wp + 20723712);         // 3x512 f32

  dim3 blk(256);
  const int mods[3][2] = {{1, 2}, {1, 3}, {2, 3}};
  const int srcs[3][2] = {{1, 2}, {0, 2}, {0, 1}};

  // L1: prep (34176 + 32 cb blocks)
  {
    PrepArgs pa;
    pa.vh = verb_hidden; pa.ih = inst_hidden; pa.th = target_hidden;
    pa.mha_in_W = mha_in_W; pa.mha_out_W = mha_out_W;
    pa.mha_in_b = mha_in_b; pa.mha_out_b = mha_out_b;
    pa.hp_W = hp_W; pa.gate_W = gate_W; pa.fus_W1 = fus_W1; pa.fus_W2 = fus_W2;
    pa.xbf = xbf; pa.Wvbf = Wvbf; pa.hpWt = hpWt; pa.gateWt = gateWt;
    pa.fusW1t = fusW1t; pa.fusW2t = fusW2t; pa.WoT = WoT; pa.cb = cb;
    prep<<<34208, blk, 0, stream>>>(pa);
  }

  // L2: fold1 — CW_z = Wv_z @ Wo_z, write both plain and transposed bf16
  {
    GemmArgs ga{};
    for (int z = 0; z < 4; z++) {
      GemmZ& g = ga.z[z];
      g.Cb = CWplain + (size_t)z * 262144; g.CbT = CWt + (size_t)z * 262144;
      g.scale = 1.f; g.nseg = 1; g.mmax = 4;
      g.seg[0] = {Wvbf + (size_t)z * 262144, WoT + (size_t)z * 262144, 512, 512, 512};
    }
    gemm_L2<<<dim3(4, 4, 4), blk, 0, stream>>>(ga);
  }

  // L3: folded gate biases + cross bias sums (k-parallel)
  bias2_k<<<dim3(8, 1, 3), blk, 0, stream>>>(cb, gate_W, gate_b, bias2, cbsum);

  // L4: stage A (z=0..2) + fold2 G_{t,u} = 0.5*CW_m@Wbot_t (z=3..8, masked)
  {
    GemmArgs ga{};
    for (int z = 0; z < 3; z++) {
      GemmZ& g = ga.z[z];
      g.Cb = Pbig + (size_t)z * S2; g.bias = hp_b + z * 512;
      g.scale = 1.f; g.nseg = 1; g.mmax = 64;
      g.seg[0] = {xbf + (size_t)z * 8192 * 1024, hpWt + (size_t)z * 524288, 1024, 1024, 1024};
    }
    for (int idx = 0; idx < 6; idx++) {
      const int t = idx >> 1, u = idx & 1, m = mods[t][u];
      GemmZ& g = ga.z[3 + idx];
      g.Cb = Gt + (size_t)idx * 262144; g.scale = 0.5f; g.nseg = 1; g.mmax = 4;
      // A = Wbot_t^T (gateWt cols 512..1023), W = CW_m row-major
      g.seg[0] = {gateWt + (size_t)t * 524288 + 512, CWplain + (size_t)m * 262144, 1024, 512, 512};
    }
    gemm_L4<<<dim3(64, 4, 9), blk, 0, stream>>>(ga);
  }

  // L5: merged logit projections
  lproj3<<<dim3(2048, 3), blk, 0, stream>>>(verb_logits, inst_logits, target_logits,
      lp_W_verb, lp_b_verb, lp_W_inst, lp_b_inst, lp_W_target, lp_b_target,
      lp_g, lp_be, lbf);

  // L6: h = GELU(LN(P))
  row_ln<<<6144, blk, 0, stream>>>(Pbig, nullptr, nullptr, hp_g, hp_be, 512,
                                   hbf, nullptr, 0, 1);

  // L7: stage C preact = h @ CW0 + cb0 (M=24576)
  {
    GemmArgs ga{};
    GemmZ& g = ga.z[0];
    g.Cb = Pbig; g.bias = cb; g.scale = 1.f; g.nseg = 1; g.mmax = 192;
    g.seg[0] = {hbf, CWt, 512, 512, 512};
    gemm_L7<<<dim3(192, 4, 1), blk, 0, stream>>>(ga);
  }
  // L8: e = LN(h + P)
  row_ln<<<6144, blk, 0, stream>>>(Pbig, hbf, nullptr, n1_g, n1_be, 512,
                                   ebf, nullptr, 1, 0);

  // L9: merged cross-sums msum_t (z=0..2, nseg=2) + gate (z=3..5, nseg=3)
  {
    GemmArgs ga{};
    for (int t = 0; t < 3; t++) {
      GemmZ& g = ga.z[t];
      g.Cb = crossbf + (size_t)t * S2;
      g.bias = cbsum + t * 512; g.scale = 0.5f; g.nseg = 2; g.mmax = 64;
      g.seg[0] = {ebf + (size_t)srcs[t][0] * S2, CWt + (size_t)mods[t][0] * 262144, 512, 512, 512};
      g.seg[1] = {ebf + (size_t)srcs[t][1] * S2, CWt + (size_t)mods[t][1] * 262144, 512, 512, 512};
    }
    for (int t = 0; t < 3; t++) {
      GemmZ& g = ga.z[3 + t];
      g.Cb = Pbig + (size_t)t * S2; g.bias = bias2 + t * 512;
      g.scale = 1.f; g.nseg = 3; g.mmax = 64;
      g.seg[0] = {ebf + (size_t)t * S2,           gateWt + (size_t)t * 524288, 512, 1024, 512};
      g.seg[1] = {ebf + (size_t)srcs[t][0] * S2,  Gt + (size_t)(2 * t) * 262144,     512, 512, 512};
      g.seg[2] = {ebf + (size_t)srcs[t][1] * S2,  Gt + (size_t)(2 * t + 1) * 262144, 512, 512, 512};
    }
    gemm_L9<<<dim3(64, 4, 6), blk, 0, stream>>>(ga);
  }

  // L10: f = LN(e + sigmoid(P)*msum)
  row_ln<<<6144, blk, 0, stream>>>(Pbig, ebf, crossbf, n2_g, n2_be, 512,
                                   fbf, nullptr, 2, 0);

  // L11: fus1 preact = [f0,f1,f2,l0,l1,l2] @ fus_W1 + b1 (6 segments)
  {
    GemmArgs ga{};
    GemmZ& g = ga.z[0];
    g.Cb = Pbig; g.bias = fus_b1; g.scale = 1.f; g.nseg = 6; g.mmax = 128;
    g.seg[0] = {fbf,                          fusW1t,        512, 2304, 512};
    g.seg[1] = {fbf + S2,                     fusW1t + 512,  512, 2304, 512};
    g.seg[2] = {fbf + 2 * S2,                 fusW1t + 1024, 512, 2304, 512};
    g.seg[3] = {lbf,                          fusW1t + 1536, 256, 2304, 256};
    g.seg[4] = {lbf + (size_t)8192 * 256,     fusW1t + 1792, 256, 2304, 256};
    g.seg[5] = {lbf + (size_t)2 * 8192 * 256, fusW1t + 2048, 256, 2304, 256};
    gemm_L11<<<dim3(128, 4, 1), blk, 0, stream>>>(ga);
  }
  // L12: g = GELU(LN(P))
  row_ln<<<2048, blk, 0, stream>>>(Pbig, nullptr, nullptr, fus_g1, fus_ge1, 0,
                                   gbf, nullptr, 0, 1);
  // L13: fus2 preact
  {
    GemmArgs ga{};
    GemmZ& g = ga.z[0];
    g.Cb = Pbig; g.bias = fus_b2; g.scale = 1.f; g.nseg = 1; g.mmax = 128;
    g.seg[0] = {gbf, fusW2t, 512, 512, 512};
    gemm_L13<<<dim3(128, 4, 1), blk, 0, stream>>>(ga);
  }
  // L14: out = LN(P), f32
  row_ln<<<2048, blk, 0, stream>>>(Pbig, nullptr, nullptr, fus_g2, fus_ge2, 0,
                                   nullptr, (float*)d_out, 0, 0);
}